// Round 12
// baseline (720.207 us; speedup 1.0000x reference)
//
#include <hip/hip_runtime.h>

#define NN 100000   // nodes
#define NF 128      // input features
#define D  64       // hidden dim
#define NE 1600000  // edges
#define NZ 1000000  // hypergraph incidences
#define NH 50000    // hyperedges

#define NS (NN + NH + NN)          // 250000 concatenated id space
#define TOT (NE + 2 * NZ)          // 3600000 adjacency entries
#define NBUK 977                   // ceil(NS/256) buckets of 256 ids
#define NWG1 256                   // phase-1 workgroups
#define P2CAP 6144                 // max entries per bucket

static __device__ __forceinline__ float waveReduceSum(float v) {
#pragma unroll
  for (int off = 32; off > 0; off >>= 1) v += __shfl_down(v, off);
  return v;
}

// Wave-uniform broadcast via readlane (VALU pipe, not ds_bpermute/LDS pipe).
static __device__ __forceinline__ float bcastf(float v, int l) {
  return __int_as_float(__builtin_amdgcn_readlane(__float_as_int(v), l));
}

// ---------------------------------------------------------------------------
// sv[0:64)   u    = conv2_W @ v1          (v1 = lp_W[:64] @ head_W)
// sv[64:128) w2v  = cls_W  @ v2           (v2 = lp_W[64:] @ head_W)
// sv[128]    c_all= lp_b.head_W + head_b + conv2_b.v1 + cls_b.v2
// ---------------------------------------------------------------------------
__global__ void k_vecs(const float* __restrict__ conv2_W, const float* __restrict__ conv2_b,
                       const float* __restrict__ cls_W, const float* __restrict__ cls_b,
                       const float* __restrict__ lp_W, const float* __restrict__ lp_b,
                       const float* __restrict__ head_W, const float* __restrict__ head_b,
                       float* __restrict__ sv) {
  int t = threadIdx.x;  // 0..63, one wave
  __shared__ float v1[64], v2[64];
  float a1 = 0.f, a2 = 0.f;
  for (int c = 0; c < 64; ++c) {
    float hw = head_W[c];
    a1 = fmaf(lp_W[t * 64 + c], hw, a1);
    a2 = fmaf(lp_W[(64 + t) * 64 + c], hw, a2);
  }
  v1[t] = a1;
  v2[t] = a2;
  __syncthreads();
  float u = 0.f, w = 0.f;
  for (int c = 0; c < 64; ++c) {
    u = fmaf(conv2_W[t * 64 + c], v1[c], u);
    w = fmaf(cls_W[t * 64 + c], v2[c], w);
  }
  sv[t] = u;
  sv[64 + t] = w;
  float part = lp_b[t] * head_W[t] + conv2_b[t] * v1[t] + cls_b[t] * v2[t];
  part = waveReduceSum(part);
  if (t == 0) sv[128] = part + head_b[0];
}

// ---------------------------------------------------------------------------
// Tall-skinny GEMM: out[r,c] = scale?*(act(in[r,:K] @ W[K,64] + b[c]))
// readlane broadcast (VALU) + next-row prefetch.  [R7-proven]
// ---------------------------------------------------------------------------
template <int K, bool BIAS, bool RELU, bool SCALE>
__global__ __launch_bounds__(256) void k_gemm(const float* __restrict__ in,
                                              const float* __restrict__ W,
                                              const float* __restrict__ bias,
                                              const float* __restrict__ scale,
                                              float* __restrict__ out, int nrows) {
  int lane = threadIdx.x & 63;
  int wave = threadIdx.x >> 6;
  float w[K];
#pragma unroll
  for (int k = 0; k < K; ++k) w[k] = W[k * 64 + lane];
  float b = BIAS ? bias[lane] : 0.0f;
  int wid = blockIdx.x * 4 + wave;
  int nw = gridDim.x * 4;
  if (wid >= nrows) return;
  float v0 = in[(size_t)wid * K + lane];
  float v1 = 0.f;
  if constexpr (K == 128) v1 = in[(size_t)wid * K + 64 + lane];
  for (int row = wid; row < nrows; row += nw) {
    int nrow = row + nw;
    float nv0 = 0.f, nv1 = 0.f;
    if (nrow < nrows) {
      nv0 = in[(size_t)nrow * K + lane];
      if constexpr (K == 128) nv1 = in[(size_t)nrow * K + 64 + lane];
    }
    float acc0 = b, acc1 = 0.f;
#pragma unroll
    for (int k = 0; k < 64; k += 2) {
      acc0 = fmaf(bcastf(v0, k), w[k], acc0);
      acc1 = fmaf(bcastf(v0, k + 1), w[k + 1], acc1);
    }
    if constexpr (K == 128) {
#pragma unroll
      for (int k = 0; k < 64; k += 2) {
        acc0 = fmaf(bcastf(v1, k), w[64 + k], acc0);
        acc1 = fmaf(bcastf(v1, k + 1), w[64 + k + 1], acc1);
      }
    }
    float r = acc0 + acc1;
    if (RELU) r = fmaxf(r, 0.0f);
    if (SCALE) r *= scale[row];
    out[(size_t)row * 64 + lane] = r;
    v0 = nv0;
    v1 = nv1;
  }
}

// ---------------------------------------------------------------------------
// CSR build: LDS-binned counting sort.
// ---------------------------------------------------------------------------
__global__ __launch_bounds__(256) void k_ccount(const int* __restrict__ dst,
                                                const int* __restrict__ he,
                                                const int* __restrict__ hv,
                                                int* __restrict__ gcnt) {
  __shared__ int hist[NBUK];
  for (int b = threadIdx.x; b < NBUK; b += 256) hist[b] = 0;
  __syncthreads();
  int step = gridDim.x * 256;
  for (int j = blockIdx.x * 256 + threadIdx.x; j < TOT; j += step) {
    int id;
    if (j < NE) id = dst[j];
    else if (j < NE + NZ) id = NN + he[j - NE];
    else id = NN + NH + hv[j - NE - NZ];
    atomicAdd(&hist[id >> 8], 1);
  }
  __syncthreads();
  for (int b = threadIdx.x; b < NBUK; b += 256) {
    int c = hist[b];
    if (c) atomicAdd(&gcnt[b], c);
  }
}

__global__ __launch_bounds__(1024) void k_cscan(const int* __restrict__ gcnt,
                                                int* __restrict__ gbase,
                                                int* __restrict__ gcur) {
  __shared__ int sh[1024];
  int t = threadIdx.x;
  int v = (t < NBUK) ? gcnt[t] : 0;
  sh[t] = v;
  __syncthreads();
#pragma unroll
  for (int d = 1; d < 1024; d <<= 1) {
    int x = (t >= d) ? sh[t - d] : 0;
    __syncthreads();
    sh[t] += x;
    __syncthreads();
  }
  int excl = sh[t] - v;
  if (t < NBUK) {
    gbase[t] = excl;
    gcur[t] = excl;
  }
  if (t == 1023) gbase[NBUK] = sh[1023];
}

__global__ __launch_bounds__(1024) void k_phase1(const int* __restrict__ src,
                                                 const int* __restrict__ dst,
                                                 const int* __restrict__ he,
                                                 const int* __restrict__ hv,
                                                 int* __restrict__ gcur,
                                                 int* __restrict__ adj) {
  __shared__ int cnt[NBUK], base[NBUK], cur[NBUK];
  int tid = threadIdx.x;
  for (int b = tid; b < NBUK; b += 1024) { cnt[b] = 0; cur[b] = 0; }
  __syncthreads();
  int per = (TOT + NWG1 - 1) / NWG1;
  int s0 = blockIdx.x * per;
  int s1 = s0 + per; if (s1 > TOT) s1 = TOT;
  for (int j = s0 + tid; j < s1; j += 1024) {
    int id;
    if (j < NE) id = dst[j];
    else if (j < NE + NZ) id = NN + he[j - NE];
    else id = NN + NH + hv[j - NE - NZ];
    atomicAdd(&cnt[id >> 8], 1);
  }
  __syncthreads();
  for (int b = tid; b < NBUK; b += 1024) {
    int c = cnt[b];
    if (c) base[b] = atomicAdd(&gcur[b], c);
  }
  __syncthreads();
  for (int j = s0 + tid; j < s1; j += 1024) {
    int id, val;
    if (j < NE)           { id = dst[j];                val = src[j]; }
    else if (j < NE + NZ) { id = NN + he[j - NE];       val = hv[j - NE]; }
    else                  { id = NN + NH + hv[j - NE - NZ]; val = he[j - NE - NZ]; }
    int b = id >> 8;
    int slot = base[b] + atomicAdd(&cur[b], 1);
    adj[slot] = ((id & 255) << 17) | val;   // val < 131072
  }
}

__global__ __launch_bounds__(256) void k_phase2(const int* __restrict__ gbase,
                                                int* __restrict__ adj,
                                                int* __restrict__ off) {
  __shared__ int ent[P2CAP];
  __shared__ int hist[256];
  int b = blockIdx.x, tid = threadIdx.x;
  int s = gbase[b];
  int n = gbase[b + 1] - s;
  if (n > P2CAP) n = P2CAP;  // safety; cannot trigger on this dataset
  hist[tid] = 0;
  __syncthreads();
  for (int k = tid; k < n; k += 256) {
    int v = adj[s + k];
    ent[k] = v;
    atomicAdd(&hist[v >> 17], 1);
  }
  __syncthreads();
  int c = hist[tid];
#pragma unroll
  for (int d = 1; d < 256; d <<= 1) {
    int x = (tid >= d) ? hist[tid - d] : 0;
    __syncthreads();
    hist[tid] += x;
    __syncthreads();
  }
  int excl = hist[tid] - c;
  hist[tid] = excl;
  int gid = (b << 8) + tid;
  if (gid <= NS) off[gid] = s + excl;
  __syncthreads();
  for (int k = tid; k < n; k += 256) {
    int v = ent[k];
    int pos = atomicAdd(&hist[v >> 17], 1);
    adj[s + pos] = v & 0x1FFFF;   // store bare value
  }
}

__global__ void k_dinv(const int* __restrict__ off, float* __restrict__ dinv) {
  int i = blockIdx.x * 256 + threadIdx.x;
  if (i < NN) dinv[i] = rsqrtf((float)(off[i + 1] - off[i] + 1));  // +1 self-loop
}

// ---------------------------------------------------------------------------
// Predicated batched row-gather (8 in flight).  [R10-proven]
// Uses `beg`, `end`, `adj`, `lane` from enclosing scope.
// ---------------------------------------------------------------------------
#define GATHER_ROWS8(ROWS, ACCUM_STMT)                                  \
  for (int j0 = beg; j0 < end; j0 += 64) {                              \
    int m = end - j0; if (m > 64) m = 64;                               \
    int a = (lane < m) ? adj[j0 + lane] : 0;                            \
    for (int k = 0; k < m; k += 8) {                                    \
      int s_[8]; float r_[8];                                           \
      _Pragma("unroll")                                                 \
      for (int q = 0; q < 8; ++q) {                                     \
        int kk = k + q; kk = (kk < m - 1) ? kk : (m - 1);               \
        s_[q] = __shfl(a, kk);                                          \
      }                                                                 \
      _Pragma("unroll")                                                 \
      for (int q = 0; q < 8; ++q) r_[q] = ROWS[(size_t)s_[q] * 64 + lane]; \
      _Pragma("unroll")                                                 \
      for (int q = 0; q < 8; ++q) {                                     \
        if (k + q < m) { ACCUM_STMT(r_[q]); }                           \
      }                                                                 \
    }                                                                   \
  }

// ---------------------------------------------------------------------------
// conv1 gather, DOUBLE-BUFFERED batches: issue batch k+8/k+16 before
// accumulating batch k -> compiler emits counted vmcnt, ~2x MLP.
//   t'[i] = dinv[i] * ( relu( dinv[i]*(sum_s xw1p[s] + xw1p[i]) + conv1_b ) . u )
// ---------------------------------------------------------------------------
__global__ __launch_bounds__(256) void k_gcn1_gather(const int* __restrict__ off,
                                                     const int* __restrict__ adj,
                                                     const float* __restrict__ xw1p,
                                                     const float* __restrict__ dinv,
                                                     const float* __restrict__ conv1_b,
                                                     const float* __restrict__ sv,
                                                     float* __restrict__ tp) {
  int i = blockIdx.x * 4 + (threadIdx.x >> 6);
  if (i >= NN) return;
  int lane = threadIdx.x & 63;
  int beg = off[i], end = off[i + 1];
  float acc = 0.f;
  for (int j0 = beg; j0 < end; j0 += 64) {
    int m = end - j0; if (m > 64) m = 64;
    int a = (lane < m) ? adj[j0 + lane] : 0;
    float rA[8], rB[8];
    // prologue: batch 0 -> A
#pragma unroll
    for (int q = 0; q < 8; ++q) {
      int kk = (q < m - 1) ? q : (m - 1);
      rA[q] = xw1p[(size_t)__shfl(a, kk) * 64 + lane];
    }
    for (int k = 0; k < m; k += 16) {
      if (k + 8 < m) {            // issue batch k+8 -> B
#pragma unroll
        for (int q = 0; q < 8; ++q) {
          int kk = k + 8 + q; kk = (kk < m - 1) ? kk : (m - 1);
          rB[q] = xw1p[(size_t)__shfl(a, kk) * 64 + lane];
        }
      }
#pragma unroll
      for (int q = 0; q < 8; ++q)   // accumulate batch k (A)
        if (k + q < m) acc += rA[q];
      if (k + 16 < m) {           // issue batch k+16 -> A
#pragma unroll
        for (int q = 0; q < 8; ++q) {
          int kk = k + 16 + q; kk = (kk < m - 1) ? kk : (m - 1);
          rA[q] = xw1p[(size_t)__shfl(a, kk) * 64 + lane];
        }
      }
      if (k + 8 < m) {
#pragma unroll
        for (int q = 0; q < 8; ++q) // accumulate batch k+8 (B)
          if (k + 8 + q < m) acc += rB[q];
      }
    }
  }
  float di = dinv[i];
  float r = fmaxf(fmaf(acc + xw1p[(size_t)i * 64 + lane], di, conv1_b[lane]), 0.f);
  float p = waveReduceSum(r * sv[lane]);
  if (lane == 0) tp[i] = p * di;
}

// ---------------------------------------------------------------------------
// Xe gather + batched matvec. One wave handles 4 hyperedges (grid 3125 ->
// full occupancy). phase B: broadcasts split between readlane (VALU) and
// uniform-address ds_read (LDS pipe) to balance the two pipes.
// ---------------------------------------------------------------------------
__global__ __launch_bounds__(256) void k_xe_gather(const int* __restrict__ off,
                                                   const int* __restrict__ adj,
                                                   const float* __restrict__ C,
                                                   const float* __restrict__ W2,
                                                   const float* __restrict__ b2,
                                                   float* __restrict__ B) {
  __shared__ float hp[4][4][64];
  int lane = threadIdx.x & 63, wv = threadIdx.x >> 6;
  int base = (blockIdx.x * 4 + wv) * 4;
  if (base >= NH) return;
  int ncnt = NH - base; if (ncnt > 4) ncnt = 4;
  for (int n = 0; n < ncnt; ++n) {
    int e = base + n;
    int beg = off[NN + e], end = off[NN + e + 1];
    float acc = 0.f;
#define ACC_ADD(r) acc += (r)
    GATHER_ROWS8(C, ACC_ADD)
#undef ACC_ADD
    hp[wv][n][lane] = acc / fmaxf((float)(end - beg), 1.0f);
  }
  float hv_[4];
#pragma unroll
  for (int n = 0; n < 4; ++n) hv_[n] = hp[wv][n][lane];
  float bb = b2[lane];
  float acc[4];
#pragma unroll
  for (int n = 0; n < 4; ++n) acc[n] = bb;
  for (int k = 0; k < 64; k += 2) {
    float wk0 = W2[(64 + k) * 64 + lane];
    float wk1 = W2[(65 + k) * 64 + lane];
#pragma unroll
    for (int n = 0; n < 4; ++n) acc[n] = fmaf(bcastf(hv_[n], k), wk0, acc[n]);
#pragma unroll
    for (int n = 0; n < 4; ++n) acc[n] = fmaf(hp[wv][n][k + 1], wk1, acc[n]);
  }
#pragma unroll
  for (int n = 0; n < 4; ++n)
    if (n < ncnt) B[(size_t)(base + n) * 64 + lane] = acc[n];
}

// ---------------------------------------------------------------------------
// Final fused kernel. One wave handles 8 nodes (grid 3125 -> full occupancy).
// phase A (per node): xv-gather (predicated 8-deep) -> hpre in LDS;
//                     gcn2 scalar gather -> per-node scalar into LDS.
// phase B: matvec with pipe-balanced broadcast (readlane + uniform ds_read);
//          out = relu(hfin).w2v + scalar.
// ---------------------------------------------------------------------------
__global__ __launch_bounds__(256) void k_final(const int* __restrict__ off,
                                               const int* __restrict__ adj,
                                               const float* __restrict__ A,
                                               const float* __restrict__ B,
                                               const float* __restrict__ h,
                                               const float* __restrict__ tp,
                                               const float* __restrict__ dinv,
                                               const float* __restrict__ Wu,
                                               const float* __restrict__ bu,
                                               const float* __restrict__ sv,
                                               float* __restrict__ out) {
  __shared__ float hp[4][8][64];
  __shared__ float sarr[4][8];
  int lane = threadIdx.x & 63, wv = threadIdx.x >> 6;
  int base = (blockIdx.x * 4 + wv) * 8;
  if (base >= NN) return;
  int ncnt = NN - base; if (ncnt > 8) ncnt = 8;
  float c_all = sv[128];
  for (int n = 0; n < ncnt; ++n) {
    int i = base + n;
    float av = A[(size_t)i * 64 + lane];
    int beg = off[NN + NH + i], end = off[NN + NH + i + 1];
    float accm = 0.f;
#define ACC_RELU(r) accm += fmaxf(av + (r), 0.f)
    GATHER_ROWS8(B, ACC_RELU)
#undef ACC_RELU
    hp[wv][n][lane] = accm * (0.5f / fmaxf((float)(end - beg), 1.0f)) +
                      0.5f * h[(size_t)i * 64 + lane];
    // gcn2 scalar gather over dst-CSR
    float di = dinv[i];
    int db = off[i], de = off[i + 1];
    float g = 0.f;
    for (int j = db + lane; j < de; j += 64) g += tp[adj[j]];
    float gr = waveReduceSum(g);
    if (lane == 0) sarr[wv][n] = gr * di + tp[i] * di + c_all;
  }
  float hv_[8];
#pragma unroll
  for (int n = 0; n < 8; ++n) hv_[n] = hp[wv][n][lane];
  float bb = bu[lane];
  float w2v = sv[64 + lane];
  float acc[8];
#pragma unroll
  for (int n = 0; n < 8; ++n) acc[n] = bb;
  for (int k = 0; k < 64; k += 2) {
    float wk0 = Wu[k * 64 + lane];
    float wk1 = Wu[(k + 1) * 64 + lane];
#pragma unroll
    for (int n = 0; n < 8; ++n) acc[n] = fmaf(bcastf(hv_[n], k), wk0, acc[n]);
#pragma unroll
    for (int n = 0; n < 8; ++n) acc[n] = fmaf(hp[wv][n][k + 1], wk1, acc[n]);
  }
#pragma unroll
  for (int n = 0; n < 8; ++n) {
    if (n < ncnt) {
      float part = fmaxf(acc[n], 0.f) * w2v;
      float tot = waveReduceSum(part);
      if (lane == 0) out[base + n] = tot + sarr[wv][n];
    }
  }
}

// ---------------------------------------------------------------------------
extern "C" void kernel_launch(void* const* d_in, const int* in_sizes, int n_in,
                              void* d_out, int out_size, void* d_ws, size_t ws_size,
                              hipStream_t stream) {
  (void)in_sizes; (void)n_in; (void)out_size; (void)ws_size;
  const float* x       = (const float*)d_in[0];
  const int*   ei      = (const int*)d_in[1];
  const int*   hv      = (const int*)d_in[2];
  const int*   he      = (const int*)d_in[3];
  const float* conv1_W = (const float*)d_in[5];
  const float* conv1_b = (const float*)d_in[6];
  const float* conv2_W = (const float*)d_in[7];
  const float* conv2_b = (const float*)d_in[8];
  const float* lin_W   = (const float*)d_in[9];
  const float* lin_b   = (const float*)d_in[10];
  const float* W1      = (const float*)d_in[11];
  const float* b1      = (const float*)d_in[12];
  const float* W2      = (const float*)d_in[13];
  const float* b2      = (const float*)d_in[14];
  const float* Wu      = (const float*)d_in[15];
  const float* bu      = (const float*)d_in[16];
  const float* cls_W   = (const float*)d_in[17];
  const float* cls_b   = (const float*)d_in[18];
  const float* lp_W    = (const float*)d_in[19];
  const float* lp_b    = (const float*)d_in[20];
  const float* head_W  = (const float*)d_in[21];
  const float* head_b  = (const float*)d_in[22];
  const int* src = ei;
  const int* dst = ei + NE;
  float* out = (float*)d_out;

  // workspace (4B units). Aliasing: P = xw1' -> C.
  float* H     = (float*)d_ws;             // N*64
  float* P     = H + (size_t)NN * 64;      // N*64   xw1' then C
  float* Q     = P + (size_t)NN * 64;      // N*64   A
  float* XE    = Q + (size_t)NN * 64;      // NH*64  B
  float* DINV  = XE + (size_t)NH * 64;     // N
  float* TP    = DINV + NN;                // N   t' = t*dinv
  float* SV    = TP + NN;                  // 192
  int* GCNT    = (int*)(SV + 192);         // NBUK
  int* GBASE   = GCNT + NBUK;              // NBUK+1
  int* GCUR    = GBASE + NBUK + 1;         // NBUK
  int* OFF     = GCUR + NBUK;              // NS+1
  int* ADJ     = OFF + NS + 1;             // TOT
  // total ~95 MiB

  hipMemsetAsync(GCNT, 0, NBUK * 4, stream);

  k_vecs<<<1, 64, 0, stream>>>(conv2_W, conv2_b, cls_W, cls_b, lp_W, lp_b, head_W, head_b, SV);

  // CSR build (LDS-binned counting sort)
  k_ccount<<<512, 256, 0, stream>>>(dst, he, hv, GCNT);
  k_cscan<<<1, 1024, 0, stream>>>(GCNT, GBASE, GCUR);
  k_phase1<<<NWG1, 1024, 0, stream>>>(src, dst, he, hv, GCUR, ADJ);
  k_phase2<<<NBUK, 256, 0, stream>>>(GBASE, ADJ, OFF);
  k_dinv<<<(NN + 255) / 256, 256, 0, stream>>>(OFF, DINV);

  // dense: xw1' = (x @ conv1_W) * dinv[row]; h = relu(x @ lin_W + lin_b)
  k_gemm<128, false, false, true><<<2048, 256, 0, stream>>>(x, conv1_W, nullptr, DINV, P, NN);
  k_gemm<128, true, true, false><<<2048, 256, 0, stream>>>(x, lin_W, lin_b, nullptr, H, NN);

  // GCN branch collapsed to t' (conv2 folded into k_final)
  k_gcn1_gather<<<NN / 4, 256, 0, stream>>>(OFF, ADJ, P, DINV, conv1_b, SV, TP);

  // hyper branch dense parts: A = h @ W2[:64] (Q), C = h @ W1 + b1 (P)
  k_gemm<64, false, false, false><<<2048, 256, 0, stream>>>(H, W2, nullptr, nullptr, Q, NN);
  k_gemm<64, true, false, false><<<2048, 256, 0, stream>>>(H, W1, b1, nullptr, P, NN);

  // 4 hyperedges per wave -> 12500 waves -> 3125 blocks (full occupancy)
  k_xe_gather<<<3125, 256, 0, stream>>>(OFF, ADJ, P, W2, b2, XE);

  // 8 nodes per wave -> 12500 waves -> 3125 blocks (full occupancy)
  k_final<<<3125, 256, 0, stream>>>(OFF, ADJ, Q, XE, H, TP, DINV, Wu, bu, SV, out);
}

// Round 13
// 427.681 us; speedup vs baseline: 1.6840x; 1.6840x over previous
//
#include <hip/hip_runtime.h>

#define NN 100000   // nodes
#define NF 128      // input features
#define D  64       // hidden dim
#define NE 1600000  // edges
#define NZ 1000000  // hypergraph incidences
#define NH 50000    // hyperedges

#define NS (NN + NH + NN)          // 250000 concatenated id space
#define TOT (NE + 2 * NZ)          // 3600000 adjacency entries
#define NBUK 977                   // ceil(NS/256) buckets of 256 ids
#define NWG1 256                   // phase-1 workgroups
#define P2CAP 6144                 // max entries per bucket

static __device__ __forceinline__ float waveReduceSum(float v) {
#pragma unroll
  for (int off = 32; off > 0; off >>= 1) v += __shfl_down(v, off);
  return v;
}

// Wave-uniform broadcast via readlane (VALU pipe, not ds_bpermute/LDS pipe).
static __device__ __forceinline__ float bcastf(float v, int l) {
  return __int_as_float(__builtin_amdgcn_readlane(__float_as_int(v), l));
}

// ---------------------------------------------------------------------------
// sv[0:64)   u    = conv2_W @ v1          (v1 = lp_W[:64] @ head_W)
// sv[64:128) w2v  = cls_W  @ v2           (v2 = lp_W[64:] @ head_W)
// sv[128]    c_all= lp_b.head_W + head_b + conv2_b.v1 + cls_b.v2
// ---------------------------------------------------------------------------
__global__ void k_vecs(const float* __restrict__ conv2_W, const float* __restrict__ conv2_b,
                       const float* __restrict__ cls_W, const float* __restrict__ cls_b,
                       const float* __restrict__ lp_W, const float* __restrict__ lp_b,
                       const float* __restrict__ head_W, const float* __restrict__ head_b,
                       float* __restrict__ sv) {
  int t = threadIdx.x;  // 0..63, one wave
  __shared__ float v1[64], v2[64];
  float a1 = 0.f, a2 = 0.f;
  for (int c = 0; c < 64; ++c) {
    float hw = head_W[c];
    a1 = fmaf(lp_W[t * 64 + c], hw, a1);
    a2 = fmaf(lp_W[(64 + t) * 64 + c], hw, a2);
  }
  v1[t] = a1;
  v2[t] = a2;
  __syncthreads();
  float u = 0.f, w = 0.f;
  for (int c = 0; c < 64; ++c) {
    u = fmaf(conv2_W[t * 64 + c], v1[c], u);
    w = fmaf(cls_W[t * 64 + c], v2[c], w);
  }
  sv[t] = u;
  sv[64 + t] = w;
  float part = lp_b[t] * head_W[t] + conv2_b[t] * v1[t] + cls_b[t] * v2[t];
  part = waveReduceSum(part);
  if (t == 0) sv[128] = part + head_b[0];
}

// ---------------------------------------------------------------------------
// Tall-skinny GEMM: out[r,c] = scale?*(act(in[r,:K] @ W[K,64] + b[c]))
// readlane broadcast (VALU) + next-row prefetch.  [R7-proven]
// ---------------------------------------------------------------------------
template <int K, bool BIAS, bool RELU, bool SCALE>
__global__ __launch_bounds__(256) void k_gemm(const float* __restrict__ in,
                                              const float* __restrict__ W,
                                              const float* __restrict__ bias,
                                              const float* __restrict__ scale,
                                              float* __restrict__ out, int nrows) {
  int lane = threadIdx.x & 63;
  int wave = threadIdx.x >> 6;
  float w[K];
#pragma unroll
  for (int k = 0; k < K; ++k) w[k] = W[k * 64 + lane];
  float b = BIAS ? bias[lane] : 0.0f;
  int wid = blockIdx.x * 4 + wave;
  int nw = gridDim.x * 4;
  if (wid >= nrows) return;
  float v0 = in[(size_t)wid * K + lane];
  float v1 = 0.f;
  if constexpr (K == 128) v1 = in[(size_t)wid * K + 64 + lane];
  for (int row = wid; row < nrows; row += nw) {
    int nrow = row + nw;
    float nv0 = 0.f, nv1 = 0.f;
    if (nrow < nrows) {
      nv0 = in[(size_t)nrow * K + lane];
      if constexpr (K == 128) nv1 = in[(size_t)nrow * K + 64 + lane];
    }
    float acc0 = b, acc1 = 0.f;
#pragma unroll
    for (int k = 0; k < 64; k += 2) {
      acc0 = fmaf(bcastf(v0, k), w[k], acc0);
      acc1 = fmaf(bcastf(v0, k + 1), w[k + 1], acc1);
    }
    if constexpr (K == 128) {
#pragma unroll
      for (int k = 0; k < 64; k += 2) {
        acc0 = fmaf(bcastf(v1, k), w[64 + k], acc0);
        acc1 = fmaf(bcastf(v1, k + 1), w[64 + k + 1], acc1);
      }
    }
    float r = acc0 + acc1;
    if (RELU) r = fmaxf(r, 0.0f);
    if (SCALE) r *= scale[row];
    out[(size_t)row * 64 + lane] = r;
    v0 = nv0;
    v1 = nv1;
  }
}

// ---------------------------------------------------------------------------
// CSR build: LDS-binned counting sort.
// ---------------------------------------------------------------------------
__global__ __launch_bounds__(256) void k_ccount(const int* __restrict__ dst,
                                                const int* __restrict__ he,
                                                const int* __restrict__ hv,
                                                int* __restrict__ gcnt) {
  __shared__ int hist[NBUK];
  for (int b = threadIdx.x; b < NBUK; b += 256) hist[b] = 0;
  __syncthreads();
  int step = gridDim.x * 256;
  for (int j = blockIdx.x * 256 + threadIdx.x; j < TOT; j += step) {
    int id;
    if (j < NE) id = dst[j];
    else if (j < NE + NZ) id = NN + he[j - NE];
    else id = NN + NH + hv[j - NE - NZ];
    atomicAdd(&hist[id >> 8], 1);
  }
  __syncthreads();
  for (int b = threadIdx.x; b < NBUK; b += 256) {
    int c = hist[b];
    if (c) atomicAdd(&gcnt[b], c);
  }
}

__global__ __launch_bounds__(1024) void k_cscan(const int* __restrict__ gcnt,
                                                int* __restrict__ gbase,
                                                int* __restrict__ gcur) {
  __shared__ int sh[1024];
  int t = threadIdx.x;
  int v = (t < NBUK) ? gcnt[t] : 0;
  sh[t] = v;
  __syncthreads();
#pragma unroll
  for (int d = 1; d < 1024; d <<= 1) {
    int x = (t >= d) ? sh[t - d] : 0;
    __syncthreads();
    sh[t] += x;
    __syncthreads();
  }
  int excl = sh[t] - v;
  if (t < NBUK) {
    gbase[t] = excl;
    gcur[t] = excl;
  }
  if (t == 1023) gbase[NBUK] = sh[1023];
}

__global__ __launch_bounds__(1024) void k_phase1(const int* __restrict__ src,
                                                 const int* __restrict__ dst,
                                                 const int* __restrict__ he,
                                                 const int* __restrict__ hv,
                                                 int* __restrict__ gcur,
                                                 int* __restrict__ adj) {
  __shared__ int cnt[NBUK], base[NBUK], cur[NBUK];
  int tid = threadIdx.x;
  for (int b = tid; b < NBUK; b += 1024) { cnt[b] = 0; cur[b] = 0; }
  __syncthreads();
  int per = (TOT + NWG1 - 1) / NWG1;
  int s0 = blockIdx.x * per;
  int s1 = s0 + per; if (s1 > TOT) s1 = TOT;
  for (int j = s0 + tid; j < s1; j += 1024) {
    int id;
    if (j < NE) id = dst[j];
    else if (j < NE + NZ) id = NN + he[j - NE];
    else id = NN + NH + hv[j - NE - NZ];
    atomicAdd(&cnt[id >> 8], 1);
  }
  __syncthreads();
  for (int b = tid; b < NBUK; b += 1024) {
    int c = cnt[b];
    if (c) base[b] = atomicAdd(&gcur[b], c);
  }
  __syncthreads();
  for (int j = s0 + tid; j < s1; j += 1024) {
    int id, val;
    if (j < NE)           { id = dst[j];                val = src[j]; }
    else if (j < NE + NZ) { id = NN + he[j - NE];       val = hv[j - NE]; }
    else                  { id = NN + NH + hv[j - NE - NZ]; val = he[j - NE - NZ]; }
    int b = id >> 8;
    int slot = base[b] + atomicAdd(&cur[b], 1);
    adj[slot] = ((id & 255) << 17) | val;   // val < 131072
  }
}

__global__ __launch_bounds__(256) void k_phase2(const int* __restrict__ gbase,
                                                int* __restrict__ adj,
                                                int* __restrict__ off) {
  __shared__ int ent[P2CAP];
  __shared__ int hist[256];
  int b = blockIdx.x, tid = threadIdx.x;
  int s = gbase[b];
  int n = gbase[b + 1] - s;
  if (n > P2CAP) n = P2CAP;  // safety; cannot trigger on this dataset
  hist[tid] = 0;
  __syncthreads();
  for (int k = tid; k < n; k += 256) {
    int v = adj[s + k];
    ent[k] = v;
    atomicAdd(&hist[v >> 17], 1);
  }
  __syncthreads();
  int c = hist[tid];
#pragma unroll
  for (int d = 1; d < 256; d <<= 1) {
    int x = (tid >= d) ? hist[tid - d] : 0;
    __syncthreads();
    hist[tid] += x;
    __syncthreads();
  }
  int excl = hist[tid] - c;
  hist[tid] = excl;
  int gid = (b << 8) + tid;
  if (gid <= NS) off[gid] = s + excl;
  __syncthreads();
  for (int k = tid; k < n; k += 256) {
    int v = ent[k];
    int pos = atomicAdd(&hist[v >> 17], 1);
    adj[s + pos] = v & 0x1FFFF;   // store bare value
  }
}

__global__ void k_dinv(const int* __restrict__ off, float* __restrict__ dinv) {
  int i = blockIdx.x * 256 + threadIdx.x;
  if (i < NN) dinv[i] = rsqrtf((float)(off[i + 1] - off[i] + 1));  // +1 self-loop
}

// ---------------------------------------------------------------------------
// Predicated batched row-gather (8 in flight).  [R10-proven]
// Uses `beg`, `end`, `adj`, `lane` from enclosing scope.
// ---------------------------------------------------------------------------
#define GATHER_ROWS8(ROWS, ACCUM_STMT)                                  \
  for (int j0 = beg; j0 < end; j0 += 64) {                              \
    int m = end - j0; if (m > 64) m = 64;                               \
    int a = (lane < m) ? adj[j0 + lane] : 0;                            \
    for (int k = 0; k < m; k += 8) {                                    \
      int s_[8]; float r_[8];                                           \
      _Pragma("unroll")                                                 \
      for (int q = 0; q < 8; ++q) {                                     \
        int kk = k + q; kk = (kk < m - 1) ? kk : (m - 1);               \
        s_[q] = __shfl(a, kk);                                          \
      }                                                                 \
      _Pragma("unroll")                                                 \
      for (int q = 0; q < 8; ++q) r_[q] = ROWS[(size_t)s_[q] * 64 + lane]; \
      _Pragma("unroll")                                                 \
      for (int q = 0; q < 8; ++q) {                                     \
        if (k + q < m) { ACCUM_STMT(r_[q]); }                           \
      }                                                                 \
    }                                                                   \
  }

// ---------------------------------------------------------------------------
// conv1 gather (xw1p pre-scaled by dinv[row]):  [R11-proven]
//   t'[i] = dinv[i] * ( relu( dinv[i]*(sum_s xw1p[s] + xw1p[i]) + conv1_b ) . u )
// ---------------------------------------------------------------------------
__global__ __launch_bounds__(256) void k_gcn1_gather(const int* __restrict__ off,
                                                     const int* __restrict__ adj,
                                                     const float* __restrict__ xw1p,
                                                     const float* __restrict__ dinv,
                                                     const float* __restrict__ conv1_b,
                                                     const float* __restrict__ sv,
                                                     float* __restrict__ tp) {
  int i = blockIdx.x * 4 + (threadIdx.x >> 6);
  if (i >= NN) return;
  int lane = threadIdx.x & 63;
  int beg = off[i], end = off[i + 1];
  float acc = 0.f;
#define ACC_ADD(r) acc += (r)
  GATHER_ROWS8(xw1p, ACC_ADD)
#undef ACC_ADD
  float di = dinv[i];
  float r = fmaxf(fmaf(acc + xw1p[(size_t)i * 64 + lane], di, conv1_b[lane]), 0.f);
  float p = waveReduceSum(r * sv[lane]);
  if (lane == 0) tp[i] = p * di;
}

// ---------------------------------------------------------------------------
// Xe gather + batched matvec. One wave handles 4 hyperedges (grid 3125 ->
// 12.2 blocks/CU). phase B: pure readlane matvec (R11-proven, VGPR-lean).
// ---------------------------------------------------------------------------
__global__ __launch_bounds__(256) void k_xe_gather(const int* __restrict__ off,
                                                   const int* __restrict__ adj,
                                                   const float* __restrict__ C,
                                                   const float* __restrict__ W2,
                                                   const float* __restrict__ b2,
                                                   float* __restrict__ B) {
  __shared__ float hp[4][4][64];
  int lane = threadIdx.x & 63, wv = threadIdx.x >> 6;
  int base = (blockIdx.x * 4 + wv) * 4;
  if (base >= NH) return;
  int ncnt = NH - base; if (ncnt > 4) ncnt = 4;
  for (int n = 0; n < ncnt; ++n) {
    int e = base + n;
    int beg = off[NN + e], end = off[NN + e + 1];
    float acc = 0.f;
#define ACC_ADD(r) acc += (r)
    GATHER_ROWS8(C, ACC_ADD)
#undef ACC_ADD
    hp[wv][n][lane] = acc / fmaxf((float)(end - beg), 1.0f);
  }
  // phase B: each lane re-reads its own column (static index -> registers)
  float hv_[4];
#pragma unroll
  for (int n = 0; n < 4; ++n) hv_[n] = hp[wv][n][lane];
  float bb = b2[lane];
  float acc[4];
#pragma unroll
  for (int n = 0; n < 4; ++n) acc[n] = bb;
  for (int k = 0; k < 64; ++k) {
    float wk = W2[(64 + k) * 64 + lane];
#pragma unroll
    for (int n = 0; n < 4; ++n) acc[n] = fmaf(bcastf(hv_[n], k), wk, acc[n]);
  }
#pragma unroll
  for (int n = 0; n < 4; ++n)
    if (n < ncnt) B[(size_t)(base + n) * 64 + lane] = acc[n];
}

// ---------------------------------------------------------------------------
// Final fused kernel. One wave handles 8 nodes (grid 3125 -> 12.2 blocks/CU,
// LDS 8.4KB, VGPR ~28 -> full 32-wave residency reachable).
// phase A (per node): xv-gather (predicated 8-deep) -> hpre in LDS;
//                     gcn2 scalar gather -> per-node scalar into LDS.
// phase B: pure readlane matvec (R11-proven); out = relu(hfin).w2v + scalar.
// ---------------------------------------------------------------------------
__global__ __launch_bounds__(256) void k_final(const int* __restrict__ off,
                                               const int* __restrict__ adj,
                                               const float* __restrict__ A,
                                               const float* __restrict__ B,
                                               const float* __restrict__ h,
                                               const float* __restrict__ tp,
                                               const float* __restrict__ dinv,
                                               const float* __restrict__ Wu,
                                               const float* __restrict__ bu,
                                               const float* __restrict__ sv,
                                               float* __restrict__ out) {
  __shared__ float hp[4][8][64];
  __shared__ float sarr[4][8];
  int lane = threadIdx.x & 63, wv = threadIdx.x >> 6;
  int base = (blockIdx.x * 4 + wv) * 8;
  if (base >= NN) return;
  int ncnt = NN - base; if (ncnt > 8) ncnt = 8;
  float c_all = sv[128];
  for (int n = 0; n < ncnt; ++n) {
    int i = base + n;
    float av = A[(size_t)i * 64 + lane];
    int beg = off[NN + NH + i], end = off[NN + NH + i + 1];
    float accm = 0.f;
#define ACC_RELU(r) accm += fmaxf(av + (r), 0.f)
    GATHER_ROWS8(B, ACC_RELU)
#undef ACC_RELU
    hp[wv][n][lane] = accm * (0.5f / fmaxf((float)(end - beg), 1.0f)) +
                      0.5f * h[(size_t)i * 64 + lane];
    // gcn2 scalar gather over dst-CSR
    float di = dinv[i];
    int db = off[i], de = off[i + 1];
    float g = 0.f;
    for (int j = db + lane; j < de; j += 64) g += tp[adj[j]];
    float gr = waveReduceSum(g);
    if (lane == 0) sarr[wv][n] = gr * di + tp[i] * di + c_all;
  }
  // phase B: column re-read to registers, readlane matvec on VALU pipe
  float hv_[8];
#pragma unroll
  for (int n = 0; n < 8; ++n) hv_[n] = hp[wv][n][lane];
  float bb = bu[lane];
  float w2v = sv[64 + lane];
  float acc[8];
#pragma unroll
  for (int n = 0; n < 8; ++n) acc[n] = bb;
  for (int k = 0; k < 64; ++k) {
    float wk = Wu[k * 64 + lane];
#pragma unroll
    for (int n = 0; n < 8; ++n) acc[n] = fmaf(bcastf(hv_[n], k), wk, acc[n]);
  }
#pragma unroll
  for (int n = 0; n < 8; ++n) {
    if (n < ncnt) {
      float part = fmaxf(acc[n], 0.f) * w2v;
      float tot = waveReduceSum(part);
      if (lane == 0) out[base + n] = tot + sarr[wv][n];
    }
  }
}

// ---------------------------------------------------------------------------
extern "C" void kernel_launch(void* const* d_in, const int* in_sizes, int n_in,
                              void* d_out, int out_size, void* d_ws, size_t ws_size,
                              hipStream_t stream) {
  (void)in_sizes; (void)n_in; (void)out_size; (void)ws_size;
  const float* x       = (const float*)d_in[0];
  const int*   ei      = (const int*)d_in[1];
  const int*   hv      = (const int*)d_in[2];
  const int*   he      = (const int*)d_in[3];
  const float* conv1_W = (const float*)d_in[5];
  const float* conv1_b = (const float*)d_in[6];
  const float* conv2_W = (const float*)d_in[7];
  const float* conv2_b = (const float*)d_in[8];
  const float* lin_W   = (const float*)d_in[9];
  const float* lin_b   = (const float*)d_in[10];
  const float* W1      = (const float*)d_in[11];
  const float* b1      = (const float*)d_in[12];
  const float* W2      = (const float*)d_in[13];
  const float* b2      = (const float*)d_in[14];
  const float* Wu      = (const float*)d_in[15];
  const float* bu      = (const float*)d_in[16];
  const float* cls_W   = (const float*)d_in[17];
  const float* cls_b   = (const float*)d_in[18];
  const float* lp_W    = (const float*)d_in[19];
  const float* lp_b    = (const float*)d_in[20];
  const float* head_W  = (const float*)d_in[21];
  const float* head_b  = (const float*)d_in[22];
  const int* src = ei;
  const int* dst = ei + NE;
  float* out = (float*)d_out;

  // workspace (4B units). Aliasing: P = xw1' -> C.
  float* H     = (float*)d_ws;             // N*64
  float* P     = H + (size_t)NN * 64;      // N*64   xw1' then C
  float* Q     = P + (size_t)NN * 64;      // N*64   A
  float* XE    = Q + (size_t)NN * 64;      // NH*64  B
  float* DINV  = XE + (size_t)NH * 64;     // N
  float* TP    = DINV + NN;                // N   t' = t*dinv
  float* SV    = TP + NN;                  // 192
  int* GCNT    = (int*)(SV + 192);         // NBUK
  int* GBASE   = GCNT + NBUK;              // NBUK+1
  int* GCUR    = GBASE + NBUK + 1;         // NBUK
  int* OFF     = GCUR + NBUK;              // NS+1
  int* ADJ     = OFF + NS + 1;             // TOT
  // total ~95 MiB

  hipMemsetAsync(GCNT, 0, NBUK * 4, stream);

  k_vecs<<<1, 64, 0, stream>>>(conv2_W, conv2_b, cls_W, cls_b, lp_W, lp_b, head_W, head_b, SV);

  // CSR build (LDS-binned counting sort)
  k_ccount<<<512, 256, 0, stream>>>(dst, he, hv, GCNT);
  k_cscan<<<1, 1024, 0, stream>>>(GCNT, GBASE, GCUR);
  k_phase1<<<NWG1, 1024, 0, stream>>>(src, dst, he, hv, GCUR, ADJ);
  k_phase2<<<NBUK, 256, 0, stream>>>(GBASE, ADJ, OFF);
  k_dinv<<<(NN + 255) / 256, 256, 0, stream>>>(OFF, DINV);

  // dense: xw1' = (x @ conv1_W) * dinv[row]; h = relu(x @ lin_W + lin_b)
  k_gemm<128, false, false, true><<<2048, 256, 0, stream>>>(x, conv1_W, nullptr, DINV, P, NN);
  k_gemm<128, true, true, false><<<2048, 256, 0, stream>>>(x, lin_W, lin_b, nullptr, H, NN);

  // GCN branch collapsed to t' (conv2 folded into k_final)
  k_gcn1_gather<<<NN / 4, 256, 0, stream>>>(OFF, ADJ, P, DINV, conv1_b, SV, TP);

  // hyper branch dense parts: A = h @ W2[:64] (Q), C = h @ W1 + b1 (P)
  k_gemm<64, false, false, false><<<2048, 256, 0, stream>>>(H, W2, nullptr, nullptr, Q, NN);
  k_gemm<64, true, false, false><<<2048, 256, 0, stream>>>(H, W1, b1, nullptr, P, NN);

  // 4 hyperedges per wave -> 12500 waves -> 3125 blocks
  k_xe_gather<<<3125, 256, 0, stream>>>(OFF, ADJ, P, W2, b2, XE);

  // 8 nodes per wave -> 12500 waves -> 3125 blocks
  k_final<<<3125, 256, 0, stream>>>(OFF, ADJ, Q, XE, H, TP, DINV, Wu, bu, SV, out);
}

// Round 14
// 410.895 us; speedup vs baseline: 1.7528x; 1.0409x over previous
//
#include <hip/hip_runtime.h>
#include <hip/hip_fp16.h>

#define NN 100000   // nodes
#define NF 128      // input features
#define D  64       // hidden dim
#define NE 1600000  // edges
#define NZ 1000000  // hypergraph incidences
#define NH 50000    // hyperedges

#define NS (NN + NH + NN)          // 250000 concatenated id space
#define TOT (NE + 2 * NZ)          // 3600000 adjacency entries
#define NBUK 977                   // ceil(NS/256) buckets of 256 ids
#define NWG1 256                   // phase-1 workgroups
#define P2CAP 6144                 // max entries per bucket

static __device__ __forceinline__ float waveReduceSum(float v) {
#pragma unroll
  for (int off = 32; off > 0; off >>= 1) v += __shfl_down(v, off);
  return v;
}

// Wave-uniform broadcast via readlane (VALU pipe, not ds_bpermute/LDS pipe).
static __device__ __forceinline__ float bcastf(float v, int l) {
  return __int_as_float(__builtin_amdgcn_readlane(__float_as_int(v), l));
}

// ---------------------------------------------------------------------------
// sv[0:64)   u    = conv2_W @ v1          (v1 = lp_W[:64] @ head_W)
// sv[64:128) w2v  = cls_W  @ v2           (v2 = lp_W[64:] @ head_W)
// sv[128]    c_all= lp_b.head_W + head_b + conv2_b.v1 + cls_b.v2
// ---------------------------------------------------------------------------
__global__ void k_vecs(const float* __restrict__ conv2_W, const float* __restrict__ conv2_b,
                       const float* __restrict__ cls_W, const float* __restrict__ cls_b,
                       const float* __restrict__ lp_W, const float* __restrict__ lp_b,
                       const float* __restrict__ head_W, const float* __restrict__ head_b,
                       float* __restrict__ sv) {
  int t = threadIdx.x;  // 0..63, one wave
  __shared__ float v1[64], v2[64];
  float a1 = 0.f, a2 = 0.f;
  for (int c = 0; c < 64; ++c) {
    float hw = head_W[c];
    a1 = fmaf(lp_W[t * 64 + c], hw, a1);
    a2 = fmaf(lp_W[(64 + t) * 64 + c], hw, a2);
  }
  v1[t] = a1;
  v2[t] = a2;
  __syncthreads();
  float u = 0.f, w = 0.f;
  for (int c = 0; c < 64; ++c) {
    u = fmaf(conv2_W[t * 64 + c], v1[c], u);
    w = fmaf(cls_W[t * 64 + c], v2[c], w);
  }
  sv[t] = u;
  sv[64 + t] = w;
  float part = lp_b[t] * head_W[t] + conv2_b[t] * v1[t] + cls_b[t] * v2[t];
  part = waveReduceSum(part);
  if (t == 0) sv[128] = part + head_b[0];
}

// ---------------------------------------------------------------------------
// Tall-skinny GEMM: out[r,c] = scale?*(act(in[r,:K] @ W[K,64] + b[c]))
// readlane broadcast (VALU) + next-row prefetch.  [R7-proven]
// OT = float or __half (fp16 gather tables).
// ---------------------------------------------------------------------------
template <int K, bool BIAS, bool RELU, bool SCALE, typename OT>
__global__ __launch_bounds__(256) void k_gemm(const float* __restrict__ in,
                                              const float* __restrict__ W,
                                              const float* __restrict__ bias,
                                              const float* __restrict__ scale,
                                              OT* __restrict__ out, int nrows) {
  int lane = threadIdx.x & 63;
  int wave = threadIdx.x >> 6;
  float w[K];
#pragma unroll
  for (int k = 0; k < K; ++k) w[k] = W[k * 64 + lane];
  float b = BIAS ? bias[lane] : 0.0f;
  int wid = blockIdx.x * 4 + wave;
  int nw = gridDim.x * 4;
  if (wid >= nrows) return;
  float v0 = in[(size_t)wid * K + lane];
  float v1 = 0.f;
  if constexpr (K == 128) v1 = in[(size_t)wid * K + 64 + lane];
  for (int row = wid; row < nrows; row += nw) {
    int nrow = row + nw;
    float nv0 = 0.f, nv1 = 0.f;
    if (nrow < nrows) {
      nv0 = in[(size_t)nrow * K + lane];
      if constexpr (K == 128) nv1 = in[(size_t)nrow * K + 64 + lane];
    }
    float acc0 = b, acc1 = 0.f;
#pragma unroll
    for (int k = 0; k < 64; k += 2) {
      acc0 = fmaf(bcastf(v0, k), w[k], acc0);
      acc1 = fmaf(bcastf(v0, k + 1), w[k + 1], acc1);
    }
    if constexpr (K == 128) {
#pragma unroll
      for (int k = 0; k < 64; k += 2) {
        acc0 = fmaf(bcastf(v1, k), w[64 + k], acc0);
        acc1 = fmaf(bcastf(v1, k + 1), w[64 + k + 1], acc1);
      }
    }
    float r = acc0 + acc1;
    if (RELU) r = fmaxf(r, 0.0f);
    if (SCALE) r *= scale[row];
    out[(size_t)row * 64 + lane] = (OT)r;
    v0 = nv0;
    v1 = nv1;
  }
}

// ---------------------------------------------------------------------------
// CSR build: LDS-binned counting sort.
// ---------------------------------------------------------------------------
__global__ __launch_bounds__(256) void k_ccount(const int* __restrict__ dst,
                                                const int* __restrict__ he,
                                                const int* __restrict__ hv,
                                                int* __restrict__ gcnt) {
  __shared__ int hist[NBUK];
  for (int b = threadIdx.x; b < NBUK; b += 256) hist[b] = 0;
  __syncthreads();
  int step = gridDim.x * 256;
  for (int j = blockIdx.x * 256 + threadIdx.x; j < TOT; j += step) {
    int id;
    if (j < NE) id = dst[j];
    else if (j < NE + NZ) id = NN + he[j - NE];
    else id = NN + NH + hv[j - NE - NZ];
    atomicAdd(&hist[id >> 8], 1);
  }
  __syncthreads();
  for (int b = threadIdx.x; b < NBUK; b += 256) {
    int c = hist[b];
    if (c) atomicAdd(&gcnt[b], c);
  }
}

__global__ __launch_bounds__(1024) void k_cscan(const int* __restrict__ gcnt,
                                                int* __restrict__ gbase,
                                                int* __restrict__ gcur) {
  __shared__ int sh[1024];
  int t = threadIdx.x;
  int v = (t < NBUK) ? gcnt[t] : 0;
  sh[t] = v;
  __syncthreads();
#pragma unroll
  for (int d = 1; d < 1024; d <<= 1) {
    int x = (t >= d) ? sh[t - d] : 0;
    __syncthreads();
    sh[t] += x;
    __syncthreads();
  }
  int excl = sh[t] - v;
  if (t < NBUK) {
    gbase[t] = excl;
    gcur[t] = excl;
  }
  if (t == 1023) gbase[NBUK] = sh[1023];
}

__global__ __launch_bounds__(1024) void k_phase1(const int* __restrict__ src,
                                                 const int* __restrict__ dst,
                                                 const int* __restrict__ he,
                                                 const int* __restrict__ hv,
                                                 int* __restrict__ gcur,
                                                 int* __restrict__ adj) {
  __shared__ int cnt[NBUK], base[NBUK], cur[NBUK];
  int tid = threadIdx.x;
  for (int b = tid; b < NBUK; b += 1024) { cnt[b] = 0; cur[b] = 0; }
  __syncthreads();
  int per = (TOT + NWG1 - 1) / NWG1;
  int s0 = blockIdx.x * per;
  int s1 = s0 + per; if (s1 > TOT) s1 = TOT;
  for (int j = s0 + tid; j < s1; j += 1024) {
    int id;
    if (j < NE) id = dst[j];
    else if (j < NE + NZ) id = NN + he[j - NE];
    else id = NN + NH + hv[j - NE - NZ];
    atomicAdd(&cnt[id >> 8], 1);
  }
  __syncthreads();
  for (int b = tid; b < NBUK; b += 1024) {
    int c = cnt[b];
    if (c) base[b] = atomicAdd(&gcur[b], c);
  }
  __syncthreads();
  for (int j = s0 + tid; j < s1; j += 1024) {
    int id, val;
    if (j < NE)           { id = dst[j];                val = src[j]; }
    else if (j < NE + NZ) { id = NN + he[j - NE];       val = hv[j - NE]; }
    else                  { id = NN + NH + hv[j - NE - NZ]; val = he[j - NE - NZ]; }
    int b = id >> 8;
    int slot = base[b] + atomicAdd(&cur[b], 1);
    adj[slot] = ((id & 255) << 17) | val;   // val < 131072
  }
}

__global__ __launch_bounds__(256) void k_phase2(const int* __restrict__ gbase,
                                                int* __restrict__ adj,
                                                int* __restrict__ off) {
  __shared__ int ent[P2CAP];
  __shared__ int hist[256];
  int b = blockIdx.x, tid = threadIdx.x;
  int s = gbase[b];
  int n = gbase[b + 1] - s;
  if (n > P2CAP) n = P2CAP;  // safety; cannot trigger on this dataset
  hist[tid] = 0;
  __syncthreads();
  for (int k = tid; k < n; k += 256) {
    int v = adj[s + k];
    ent[k] = v;
    atomicAdd(&hist[v >> 17], 1);
  }
  __syncthreads();
  int c = hist[tid];
#pragma unroll
  for (int d = 1; d < 256; d <<= 1) {
    int x = (tid >= d) ? hist[tid - d] : 0;
    __syncthreads();
    hist[tid] += x;
    __syncthreads();
  }
  int excl = hist[tid] - c;
  hist[tid] = excl;
  int gid = (b << 8) + tid;
  if (gid <= NS) off[gid] = s + excl;
  __syncthreads();
  for (int k = tid; k < n; k += 256) {
    int v = ent[k];
    int pos = atomicAdd(&hist[v >> 17], 1);
    adj[s + pos] = v & 0x1FFFF;   // store bare value
  }
}

__global__ void k_dinv(const int* __restrict__ off, float* __restrict__ dinv) {
  int i = blockIdx.x * 256 + threadIdx.x;
  if (i < NN) dinv[i] = rsqrtf((float)(off[i + 1] - off[i] + 1));  // +1 self-loop
}

// ---------------------------------------------------------------------------
// Predicated batched row-gather (8 in flight); ROWS may be float* or __half*.
// Uses `beg`, `end`, `adj`, `lane` from enclosing scope.  [R10-proven]
// ---------------------------------------------------------------------------
#define GATHER_ROWS8(ROWS, ACCUM_STMT)                                  \
  for (int j0 = beg; j0 < end; j0 += 64) {                              \
    int m = end - j0; if (m > 64) m = 64;                               \
    int a = (lane < m) ? adj[j0 + lane] : 0;                            \
    for (int k = 0; k < m; k += 8) {                                    \
      int s_[8]; float r_[8];                                           \
      _Pragma("unroll")                                                 \
      for (int q = 0; q < 8; ++q) {                                     \
        int kk = k + q; kk = (kk < m - 1) ? kk : (m - 1);               \
        s_[q] = __shfl(a, kk);                                          \
      }                                                                 \
      _Pragma("unroll")                                                 \
      for (int q = 0; q < 8; ++q) r_[q] = (float)ROWS[(size_t)s_[q] * 64 + lane]; \
      _Pragma("unroll")                                                 \
      for (int q = 0; q < 8; ++q) {                                     \
        if (k + q < m) { ACCUM_STMT(r_[q]); }                           \
      }                                                                 \
    }                                                                   \
  }

// ---------------------------------------------------------------------------
// conv1 gather over fp16 xw1p (pre-scaled by dinv[row]):
//   t'[i] = dinv[i] * ( relu( dinv[i]*(sum_s xw1p[s] + xw1p[i]) + conv1_b ) . u )
// ---------------------------------------------------------------------------
__global__ __launch_bounds__(256) void k_gcn1_gather(const int* __restrict__ off,
                                                     const int* __restrict__ adj,
                                                     const __half* __restrict__ xw1p,
                                                     const float* __restrict__ dinv,
                                                     const float* __restrict__ conv1_b,
                                                     const float* __restrict__ sv,
                                                     float* __restrict__ tp) {
  int i = blockIdx.x * 4 + (threadIdx.x >> 6);
  if (i >= NN) return;
  int lane = threadIdx.x & 63;
  int beg = off[i], end = off[i + 1];
  float acc = 0.f;
#define ACC_ADD(r) acc += (r)
  GATHER_ROWS8(xw1p, ACC_ADD)
#undef ACC_ADD
  float di = dinv[i];
  float selfv = (float)xw1p[(size_t)i * 64 + lane];
  float r = fmaxf(fmaf(acc + selfv, di, conv1_b[lane]), 0.f);
  float p = waveReduceSum(r * sv[lane]);
  if (lane == 0) tp[i] = p * di;
}

// ---------------------------------------------------------------------------
// Xe gather + batched matvec. 4 hyperedges/wave, grid 3125.  [R13-proven]
// Gathers fp16 C rows; phase B pure readlane matvec; writes fp16 B.
// ---------------------------------------------------------------------------
__global__ __launch_bounds__(256) void k_xe_gather(const int* __restrict__ off,
                                                   const int* __restrict__ adj,
                                                   const __half* __restrict__ C,
                                                   const float* __restrict__ W2,
                                                   const float* __restrict__ b2,
                                                   __half* __restrict__ B) {
  __shared__ float hp[4][4][64];
  int lane = threadIdx.x & 63, wv = threadIdx.x >> 6;
  int base = (blockIdx.x * 4 + wv) * 4;
  if (base >= NH) return;
  int ncnt = NH - base; if (ncnt > 4) ncnt = 4;
  for (int n = 0; n < ncnt; ++n) {
    int e = base + n;
    int beg = off[NN + e], end = off[NN + e + 1];
    float acc = 0.f;
#define ACC_ADD(r) acc += (r)
    GATHER_ROWS8(C, ACC_ADD)
#undef ACC_ADD
    hp[wv][n][lane] = acc / fmaxf((float)(end - beg), 1.0f);
  }
  float hv_[4];
#pragma unroll
  for (int n = 0; n < 4; ++n) hv_[n] = hp[wv][n][lane];
  float bb = b2[lane];
  float acc[4];
#pragma unroll
  for (int n = 0; n < 4; ++n) acc[n] = bb;
  for (int k = 0; k < 64; ++k) {
    float wk = W2[(64 + k) * 64 + lane];
#pragma unroll
    for (int n = 0; n < 4; ++n) acc[n] = fmaf(bcastf(hv_[n], k), wk, acc[n]);
  }
#pragma unroll
  for (int n = 0; n < 4; ++n)
    if (n < ncnt) B[(size_t)(base + n) * 64 + lane] = (__half)acc[n];
}

// ---------------------------------------------------------------------------
// Final fused kernel. 8 nodes/wave, grid 3125.  [R13-proven structure]
// phase A (per node): xv-gather over fp16 B rows -> hpre in LDS;
//                     gcn2 scalar gather -> per-node scalar into LDS.
// phase B: pure readlane matvec; out = relu(hfin).w2v + scalar.
// ---------------------------------------------------------------------------
__global__ __launch_bounds__(256) void k_final(const int* __restrict__ off,
                                               const int* __restrict__ adj,
                                               const float* __restrict__ A,
                                               const __half* __restrict__ B,
                                               const float* __restrict__ h,
                                               const float* __restrict__ tp,
                                               const float* __restrict__ dinv,
                                               const float* __restrict__ Wu,
                                               const float* __restrict__ bu,
                                               const float* __restrict__ sv,
                                               float* __restrict__ out) {
  __shared__ float hp[4][8][64];
  __shared__ float sarr[4][8];
  int lane = threadIdx.x & 63, wv = threadIdx.x >> 6;
  int base = (blockIdx.x * 4 + wv) * 8;
  if (base >= NN) return;
  int ncnt = NN - base; if (ncnt > 8) ncnt = 8;
  float c_all = sv[128];
  for (int n = 0; n < ncnt; ++n) {
    int i = base + n;
    float av = A[(size_t)i * 64 + lane];
    int beg = off[NN + NH + i], end = off[NN + NH + i + 1];
    float accm = 0.f;
#define ACC_RELU(r) accm += fmaxf(av + (r), 0.f)
    GATHER_ROWS8(B, ACC_RELU)
#undef ACC_RELU
    hp[wv][n][lane] = accm * (0.5f / fmaxf((float)(end - beg), 1.0f)) +
                      0.5f * h[(size_t)i * 64 + lane];
    // gcn2 scalar gather over dst-CSR
    float di = dinv[i];
    int db = off[i], de = off[i + 1];
    float g = 0.f;
    for (int j = db + lane; j < de; j += 64) g += tp[adj[j]];
    float gr = waveReduceSum(g);
    if (lane == 0) sarr[wv][n] = gr * di + tp[i] * di + c_all;
  }
  float hv_[8];
#pragma unroll
  for (int n = 0; n < 8; ++n) hv_[n] = hp[wv][n][lane];
  float bb = bu[lane];
  float w2v = sv[64 + lane];
  float acc[8];
#pragma unroll
  for (int n = 0; n < 8; ++n) acc[n] = bb;
  for (int k = 0; k < 64; ++k) {
    float wk = Wu[k * 64 + lane];
#pragma unroll
    for (int n = 0; n < 8; ++n) acc[n] = fmaf(bcastf(hv_[n], k), wk, acc[n]);
  }
#pragma unroll
  for (int n = 0; n < 8; ++n) {
    if (n < ncnt) {
      float part = fmaxf(acc[n], 0.f) * w2v;
      float tot = waveReduceSum(part);
      if (lane == 0) out[base + n] = tot + sarr[wv][n];
    }
  }
}

// ---------------------------------------------------------------------------
extern "C" void kernel_launch(void* const* d_in, const int* in_sizes, int n_in,
                              void* d_out, int out_size, void* d_ws, size_t ws_size,
                              hipStream_t stream) {
  (void)in_sizes; (void)n_in; (void)out_size; (void)ws_size;
  const float* x       = (const float*)d_in[0];
  const int*   ei      = (const int*)d_in[1];
  const int*   hv      = (const int*)d_in[2];
  const int*   he      = (const int*)d_in[3];
  const float* conv1_W = (const float*)d_in[5];
  const float* conv1_b = (const float*)d_in[6];
  const float* conv2_W = (const float*)d_in[7];
  const float* conv2_b = (const float*)d_in[8];
  const float* lin_W   = (const float*)d_in[9];
  const float* lin_b   = (const float*)d_in[10];
  const float* W1      = (const float*)d_in[11];
  const float* b1      = (const float*)d_in[12];
  const float* W2      = (const float*)d_in[13];
  const float* b2      = (const float*)d_in[14];
  const float* Wu      = (const float*)d_in[15];
  const float* bu      = (const float*)d_in[16];
  const float* cls_W   = (const float*)d_in[17];
  const float* cls_b   = (const float*)d_in[18];
  const float* lp_W    = (const float*)d_in[19];
  const float* lp_b    = (const float*)d_in[20];
  const float* head_W  = (const float*)d_in[21];
  const float* head_b  = (const float*)d_in[22];
  const int* src = ei;
  const int* dst = ei + NE;
  float* out = (float*)d_out;

  // workspace (4B units). PH (fp16, N*64) aliases P; XEH (fp16, NH*64) aliases XE.
  float* H     = (float*)d_ws;             // N*64 f32   h
  float* P     = H + (size_t)NN * 64;      // N*64       xw1' then C (as fp16)
  float* Q     = P + (size_t)NN * 64;      // N*64 f32   A
  float* XE    = Q + (size_t)NN * 64;      // NH*64      B (as fp16)
  float* DINV  = XE + (size_t)NH * 64;     // N
  float* TP    = DINV + NN;                // N   t' = t*dinv
  float* SV    = TP + NN;                  // 192
  int* GCNT    = (int*)(SV + 192);         // NBUK
  int* GBASE   = GCNT + NBUK;              // NBUK+1
  int* GCUR    = GBASE + NBUK + 1;         // NBUK
  int* OFF     = GCUR + NBUK;              // NS+1
  int* ADJ     = OFF + NS + 1;             // TOT
  __half* PH   = (__half*)P;
  __half* XEH  = (__half*)XE;

  hipMemsetAsync(GCNT, 0, NBUK * 4, stream);

  k_vecs<<<1, 64, 0, stream>>>(conv2_W, conv2_b, cls_W, cls_b, lp_W, lp_b, head_W, head_b, SV);

  // CSR build (LDS-binned counting sort)
  k_ccount<<<512, 256, 0, stream>>>(dst, he, hv, GCNT);
  k_cscan<<<1, 1024, 0, stream>>>(GCNT, GBASE, GCUR);
  k_phase1<<<NWG1, 1024, 0, stream>>>(src, dst, he, hv, GCUR, ADJ);
  k_phase2<<<NBUK, 256, 0, stream>>>(GBASE, ADJ, OFF);
  k_dinv<<<(NN + 255) / 256, 256, 0, stream>>>(OFF, DINV);

  // dense: xw1' = (x @ conv1_W) * dinv[row]  (fp16); h = relu(x @ lin_W + lin_b) (f32)
  k_gemm<128, false, false, true, __half><<<2048, 256, 0, stream>>>(x, conv1_W, nullptr, DINV, PH, NN);
  k_gemm<128, true, true, false, float><<<2048, 256, 0, stream>>>(x, lin_W, lin_b, nullptr, H, NN);

  // GCN branch collapsed to t' (conv2 folded into k_final)
  k_gcn1_gather<<<NN / 4, 256, 0, stream>>>(OFF, ADJ, PH, DINV, conv1_b, SV, TP);

  // hyper branch dense parts: A = h @ W2[:64] (f32, Q); C = h @ W1 + b1 (fp16, PH)
  k_gemm<64, false, false, false, float><<<2048, 256, 0, stream>>>(H, W2, nullptr, nullptr, Q, NN);
  k_gemm<64, true, false, false, __half><<<2048, 256, 0, stream>>>(H, W1, b1, nullptr, PH, NN);

  // 4 hyperedges per wave -> 3125 blocks
  k_xe_gather<<<3125, 256, 0, stream>>>(OFF, ADJ, PH, W2, b2, XEH);

  // 8 nodes per wave -> 3125 blocks
  k_final<<<3125, 256, 0, stream>>>(OFF, ADJ, Q, XEH, H, TP, DINV, Wu, bu, SV, out);
}

// Round 15
// 375.360 us; speedup vs baseline: 1.9187x; 1.0947x over previous
//
#include <hip/hip_runtime.h>
#include <hip/hip_fp16.h>

#define NN 100000   // nodes
#define NF 128      // input features
#define D  64       // hidden dim
#define NE 1600000  // edges
#define NZ 1000000  // hypergraph incidences
#define NH 50000    // hyperedges

#define NS (NN + NH + NN)          // 250000 concatenated id space
#define TOT (NE + 2 * NZ)          // 3600000 adjacency entries
#define NBUK 977                   // ceil(NS/256) buckets of 256 ids
#define NWG1 256                   // phase-1 workgroups
#define P2CAP 6144                 // bucket stride/capacity (mean 3686, he-buckets mean 5120, +14 sigma)

typedef _Float16 half2v __attribute__((ext_vector_type(2)));

static __device__ __forceinline__ float waveReduceSum(float v) {
#pragma unroll
  for (int off = 32; off > 0; off >>= 1) v += __shfl_down(v, off);
  return v;
}

// Wave-uniform broadcast via readlane (VALU pipe, not ds_bpermute/LDS pipe).
static __device__ __forceinline__ float bcastf(float v, int l) {
  return __int_as_float(__builtin_amdgcn_readlane(__float_as_int(v), l));
}

#if __has_builtin(__builtin_amdgcn_fdot2)
static __device__ __forceinline__ float fdot2f(half2v a, half2v b, float c) {
  return __builtin_amdgcn_fdot2(a, b, c, false);
}
#else
static __device__ __forceinline__ float fdot2f(half2v a, half2v b, float c) {
  return fmaf((float)a.x, (float)b.x, fmaf((float)a.y, (float)b.y, c));
}
#endif

// ---------------------------------------------------------------------------
// sv[0:64)   u    = conv2_W @ v1          (v1 = lp_W[:64] @ head_W)
// sv[64:128) w2v  = cls_W  @ v2           (v2 = lp_W[64:] @ head_W)
// sv[128]    c_all= lp_b.head_W + head_b + conv2_b.v1 + cls_b.v2
// ---------------------------------------------------------------------------
__global__ void k_vecs(const float* __restrict__ conv2_W, const float* __restrict__ conv2_b,
                       const float* __restrict__ cls_W, const float* __restrict__ cls_b,
                       const float* __restrict__ lp_W, const float* __restrict__ lp_b,
                       const float* __restrict__ head_W, const float* __restrict__ head_b,
                       float* __restrict__ sv) {
  int t = threadIdx.x;  // 0..63, one wave
  __shared__ float v1[64], v2[64];
  float a1 = 0.f, a2 = 0.f;
  for (int c = 0; c < 64; ++c) {
    float hw = head_W[c];
    a1 = fmaf(lp_W[t * 64 + c], hw, a1);
    a2 = fmaf(lp_W[(64 + t) * 64 + c], hw, a2);
  }
  v1[t] = a1;
  v2[t] = a2;
  __syncthreads();
  float u = 0.f, w = 0.f;
  for (int c = 0; c < 64; ++c) {
    u = fmaf(conv2_W[t * 64 + c], v1[c], u);
    w = fmaf(cls_W[t * 64 + c], v2[c], w);
  }
  sv[t] = u;
  sv[64 + t] = w;
  float part = lp_b[t] * head_W[t] + conv2_b[t] * v1[t] + cls_b[t] * v2[t];
  part = waveReduceSum(part);
  if (t == 0) sv[128] = part + head_b[0];
}

// ---------------------------------------------------------------------------
// Pack Wu and W2[64:128] rows pairwise into fp16x2 tables for fdot2 matvec:
// WUP[kk*64+lane] = pack(Wu[2kk][lane], Wu[2kk+1][lane]), kk in [0,32).
// ---------------------------------------------------------------------------
__global__ void k_pack(const float* __restrict__ Wu, const float* __restrict__ W2,
                       int* __restrict__ WUP, int* __restrict__ W2P) {
  int t = blockIdx.x * 256 + threadIdx.x;
  if (t < 2048) {
    int kk = t >> 6, lane = t & 63;
    half2v p;
    p.x = (_Float16)Wu[(2 * kk) * 64 + lane];
    p.y = (_Float16)Wu[(2 * kk + 1) * 64 + lane];
    WUP[t] = __builtin_bit_cast(int, p);
  } else if (t < 4096) {
    int u = t - 2048;
    int kk = u >> 6, lane = u & 63;
    half2v p;
    p.x = (_Float16)W2[(64 + 2 * kk) * 64 + lane];
    p.y = (_Float16)W2[(64 + 2 * kk + 1) * 64 + lane];
    W2P[u] = __builtin_bit_cast(int, p);
  }
}

// ---------------------------------------------------------------------------
// Tall-skinny GEMM: out[r,c] = scale?*(act(in[r,:K] @ W[K,64] + b[c]))
// readlane broadcast (VALU) + next-row prefetch.  [R7-proven]
// ---------------------------------------------------------------------------
template <int K, bool BIAS, bool RELU, bool SCALE, typename OT>
__global__ __launch_bounds__(256) void k_gemm(const float* __restrict__ in,
                                              const float* __restrict__ W,
                                              const float* __restrict__ bias,
                                              const float* __restrict__ scale,
                                              OT* __restrict__ out, int nrows) {
  int lane = threadIdx.x & 63;
  int wave = threadIdx.x >> 6;
  float w[K];
#pragma unroll
  for (int k = 0; k < K; ++k) w[k] = W[k * 64 + lane];
  float b = BIAS ? bias[lane] : 0.0f;
  int wid = blockIdx.x * 4 + wave;
  int nw = gridDim.x * 4;
  if (wid >= nrows) return;
  float v0 = in[(size_t)wid * K + lane];
  float v1 = 0.f;
  if constexpr (K == 128) v1 = in[(size_t)wid * K + 64 + lane];
  for (int row = wid; row < nrows; row += nw) {
    int nrow = row + nw;
    float nv0 = 0.f, nv1 = 0.f;
    if (nrow < nrows) {
      nv0 = in[(size_t)nrow * K + lane];
      if constexpr (K == 128) nv1 = in[(size_t)nrow * K + 64 + lane];
    }
    float acc0 = b, acc1 = 0.f;
#pragma unroll
    for (int k = 0; k < 64; k += 2) {
      acc0 = fmaf(bcastf(v0, k), w[k], acc0);
      acc1 = fmaf(bcastf(v0, k + 1), w[k + 1], acc1);
    }
    if constexpr (K == 128) {
#pragma unroll
      for (int k = 0; k < 64; k += 2) {
        acc0 = fmaf(bcastf(v1, k), w[64 + k], acc0);
        acc1 = fmaf(bcastf(v1, k + 1), w[64 + k + 1], acc1);
      }
    }
    float r = acc0 + acc1;
    if (RELU) r = fmaxf(r, 0.0f);
    if (SCALE) r *= scale[row];
    out[(size_t)row * 64 + lane] = (OT)r;
    v0 = nv0;
    v1 = nv1;
  }
}

// ---------------------------------------------------------------------------
// CSR build (no global scan): fixed-stride buckets at b*P2CAP.
// phase1 reserves via gcur[b] (LDS-staged); phase2 sorts within bucket and
// writes per-id [OFFB, OFFE) ranges.
// ---------------------------------------------------------------------------
__global__ __launch_bounds__(1024) void k_phase1(const int* __restrict__ src,
                                                 const int* __restrict__ dst,
                                                 const int* __restrict__ he,
                                                 const int* __restrict__ hv,
                                                 int* __restrict__ gcur,
                                                 int* __restrict__ adj) {
  __shared__ int cnt[NBUK], base[NBUK], cur[NBUK];
  int tid = threadIdx.x;
  for (int b = tid; b < NBUK; b += 1024) { cnt[b] = 0; cur[b] = 0; }
  __syncthreads();
  int per = (TOT + NWG1 - 1) / NWG1;
  int s0 = blockIdx.x * per;
  int s1 = s0 + per; if (s1 > TOT) s1 = TOT;
  for (int j = s0 + tid; j < s1; j += 1024) {
    int id;
    if (j < NE) id = dst[j];
    else if (j < NE + NZ) id = NN + he[j - NE];
    else id = NN + NH + hv[j - NE - NZ];
    atomicAdd(&cnt[id >> 8], 1);
  }
  __syncthreads();
  for (int b = tid; b < NBUK; b += 1024) {
    int c = cnt[b];
    if (c) base[b] = b * P2CAP + atomicAdd(&gcur[b], c);
  }
  __syncthreads();
  for (int j = s0 + tid; j < s1; j += 1024) {
    int id, val;
    if (j < NE)           { id = dst[j];                val = src[j]; }
    else if (j < NE + NZ) { id = NN + he[j - NE];       val = hv[j - NE]; }
    else                  { id = NN + NH + hv[j - NE - NZ]; val = he[j - NE - NZ]; }
    int b = id >> 8;
    int slot = base[b] + atomicAdd(&cur[b], 1);
    adj[slot] = ((id & 255) << 17) | val;   // val < 131072
  }
}

__global__ __launch_bounds__(256) void k_phase2(const int* __restrict__ gcur,
                                                int* __restrict__ adj,
                                                int* __restrict__ offb,
                                                int* __restrict__ offe) {
  __shared__ int ent[P2CAP];
  __shared__ int hist[256];
  int b = blockIdx.x, tid = threadIdx.x;
  int s = b * P2CAP;
  int n = gcur[b];
  if (n > P2CAP) n = P2CAP;  // safety; cannot trigger on this dataset
  hist[tid] = 0;
  __syncthreads();
  for (int k = tid; k < n; k += 256) {
    int v = adj[s + k];
    ent[k] = v;
    atomicAdd(&hist[v >> 17], 1);
  }
  __syncthreads();
  int c = hist[tid];
#pragma unroll
  for (int d = 1; d < 256; d <<= 1) {
    int x = (tid >= d) ? hist[tid - d] : 0;
    __syncthreads();
    hist[tid] += x;
    __syncthreads();
  }
  int excl = hist[tid] - c;
  hist[tid] = excl;
  int gid = (b << 8) + tid;
  if (gid < NS) {
    offb[gid] = s + excl;
    offe[gid] = s + excl + c;
  }
  __syncthreads();
  for (int k = tid; k < n; k += 256) {
    int v = ent[k];
    int pos = atomicAdd(&hist[v >> 17], 1);
    adj[s + pos] = v & 0x1FFFF;   // store bare value
  }
}

__global__ void k_dinv(const int* __restrict__ offb, const int* __restrict__ offe,
                       float* __restrict__ dinv) {
  int i = blockIdx.x * 256 + threadIdx.x;
  if (i < NN) dinv[i] = rsqrtf((float)(offe[i] - offb[i] + 1));  // +1 self-loop
}

// ---------------------------------------------------------------------------
// Predicated batched row-gather (8 in flight); ROWS may be float* or __half*.
// Uses `beg`, `end`, `adj`, `lane` from enclosing scope.  [R10-proven]
// ---------------------------------------------------------------------------
#define GATHER_ROWS8(ROWS, ACCUM_STMT)                                  \
  for (int j0 = beg; j0 < end; j0 += 64) {                              \
    int m = end - j0; if (m > 64) m = 64;                               \
    int a = (lane < m) ? adj[j0 + lane] : 0;                            \
    for (int k = 0; k < m; k += 8) {                                    \
      int s_[8]; float r_[8];                                           \
      _Pragma("unroll")                                                 \
      for (int q = 0; q < 8; ++q) {                                     \
        int kk = k + q; kk = (kk < m - 1) ? kk : (m - 1);               \
        s_[q] = __shfl(a, kk);                                          \
      }                                                                 \
      _Pragma("unroll")                                                 \
      for (int q = 0; q < 8; ++q) r_[q] = (float)ROWS[(size_t)s_[q] * 64 + lane]; \
      _Pragma("unroll")                                                 \
      for (int q = 0; q < 8; ++q) {                                     \
        if (k + q < m) { ACCUM_STMT(r_[q]); }                           \
      }                                                                 \
    }                                                                   \
  }

// ---------------------------------------------------------------------------
// conv1 gather over fp16 xw1p (pre-scaled by dinv[row]):
//   t'[i] = dinv[i] * ( relu( dinv[i]*(sum_s xw1p[s] + xw1p[i]) + conv1_b ) . u )
// ---------------------------------------------------------------------------
__global__ __launch_bounds__(256) void k_gcn1_gather(const int* __restrict__ offb,
                                                     const int* __restrict__ offe,
                                                     const int* __restrict__ adj,
                                                     const __half* __restrict__ xw1p,
                                                     const float* __restrict__ dinv,
                                                     const float* __restrict__ conv1_b,
                                                     const float* __restrict__ sv,
                                                     float* __restrict__ tp) {
  int i = blockIdx.x * 4 + (threadIdx.x >> 6);
  if (i >= NN) return;
  int lane = threadIdx.x & 63;
  int beg = offb[i], end = offe[i];
  float acc = 0.f;
#define ACC_ADD(r) acc += (r)
  GATHER_ROWS8(xw1p, ACC_ADD)
#undef ACC_ADD
  float di = dinv[i];
  float selfv = (float)xw1p[(size_t)i * 64 + lane];
  float r = fmaxf(fmaf(acc + selfv, di, conv1_b[lane]), 0.f);
  float p = waveReduceSum(r * sv[lane]);
  if (lane == 0) tp[i] = p * di;
}

// ---------------------------------------------------------------------------
// Xe gather + batched matvec. 4 hyperedges/wave, grid 3125.
// phase B: fdot2 with packed fp16 weights — 1 readlane broadcasts 2 k-values.
// ---------------------------------------------------------------------------
__global__ __launch_bounds__(256) void k_xe_gather(const int* __restrict__ offb,
                                                   const int* __restrict__ offe,
                                                   const int* __restrict__ adj,
                                                   const __half* __restrict__ C,
                                                   const int* __restrict__ W2P,
                                                   const float* __restrict__ b2,
                                                   __half* __restrict__ B) {
  __shared__ float hp[4][4][64];
  int lane = threadIdx.x & 63, wv = threadIdx.x >> 6;
  int base = (blockIdx.x * 4 + wv) * 4;
  if (base >= NH) return;
  int ncnt = NH - base; if (ncnt > 4) ncnt = 4;
  for (int n = 0; n < ncnt; ++n) {
    int e = base + n;
    int beg = offb[NN + e], end = offe[NN + e];
    float acc = 0.f;
#define ACC_ADD(r) acc += (r)
    GATHER_ROWS8(C, ACC_ADD)
#undef ACC_ADD
    hp[wv][n][lane] = acc / fmaxf((float)(end - beg), 1.0f);
  }
  int l2 = lane & 31;
  int hvp[4];
#pragma unroll
  for (int n = 0; n < 4; ++n) {
    half2v p;
    p.x = (_Float16)hp[wv][n][2 * l2];
    p.y = (_Float16)hp[wv][n][2 * l2 + 1];
    hvp[n] = __builtin_bit_cast(int, p);
  }
  float bb = b2[lane];
  float acc[4];
#pragma unroll
  for (int n = 0; n < 4; ++n) acc[n] = bb;
  for (int kk = 0; kk < 32; ++kk) {
    half2v wp = __builtin_bit_cast(half2v, W2P[kk * 64 + lane]);
#pragma unroll
    for (int n = 0; n < 4; ++n) {
      half2v hb = __builtin_bit_cast(half2v, __builtin_amdgcn_readlane(hvp[n], kk));
      acc[n] = fdot2f(hb, wp, acc[n]);
    }
  }
#pragma unroll
  for (int n = 0; n < 4; ++n)
    if (n < ncnt) B[(size_t)(base + n) * 64 + lane] = (__half)acc[n];
}

// ---------------------------------------------------------------------------
// Final fused kernel. 8 nodes/wave, grid 3125.  [R13 structure]
// phase A (per node): xv-gather over fp16 B rows -> hpre in LDS;
//                     gcn2 scalar gather -> per-node scalar into LDS.
// phase B: fdot2 matvec with packed fp16 Wu; out = relu(hfin).w2v + scalar.
// ---------------------------------------------------------------------------
__global__ __launch_bounds__(256) void k_final(const int* __restrict__ offb,
                                               const int* __restrict__ offe,
                                               const int* __restrict__ adj,
                                               const float* __restrict__ A,
                                               const __half* __restrict__ B,
                                               const float* __restrict__ h,
                                               const float* __restrict__ tp,
                                               const float* __restrict__ dinv,
                                               const int* __restrict__ WUP,
                                               const float* __restrict__ bu,
                                               const float* __restrict__ sv,
                                               float* __restrict__ out) {
  __shared__ float hp[4][8][64];
  __shared__ float sarr[4][8];
  int lane = threadIdx.x & 63, wv = threadIdx.x >> 6;
  int base = (blockIdx.x * 4 + wv) * 8;
  if (base >= NN) return;
  int ncnt = NN - base; if (ncnt > 8) ncnt = 8;
  float c_all = sv[128];
  for (int n = 0; n < ncnt; ++n) {
    int i = base + n;
    float av = A[(size_t)i * 64 + lane];
    int beg = offb[NN + NH + i], end = offe[NN + NH + i];
    float accm = 0.f;
#define ACC_RELU(r) accm += fmaxf(av + (r), 0.f)
    GATHER_ROWS8(B, ACC_RELU)
#undef ACC_RELU
    hp[wv][n][lane] = accm * (0.5f / fmaxf((float)(end - beg), 1.0f)) +
                      0.5f * h[(size_t)i * 64 + lane];
    // gcn2 scalar gather over dst-CSR
    float di = dinv[i];
    int db = offb[i], de = offe[i];
    float g = 0.f;
    for (int j = db + lane; j < de; j += 64) g += tp[adj[j]];
    float gr = waveReduceSum(g);
    if (lane == 0) sarr[wv][n] = gr * di + tp[i] * di + c_all;
  }
  int l2 = lane & 31;
  int hvp[8];
#pragma unroll
  for (int n = 0; n < 8; ++n) {
    half2v p;
    p.x = (_Float16)hp[wv][n][2 * l2];
    p.y = (_Float16)hp[wv][n][2 * l2 + 1];
    hvp[n] = __builtin_bit_cast(int, p);
  }
  float bb = bu[lane];
  float w2v = sv[64 + lane];
  float acc[8];
#pragma unroll
  for (int n = 0; n < 8; ++n) acc[n] = bb;
  for (int kk = 0; kk < 32; ++kk) {
    half2v wp = __builtin_bit_cast(half2v, WUP[kk * 64 + lane]);
#pragma unroll
    for (int n = 0; n < 8; ++n) {
      half2v hb = __builtin_bit_cast(half2v, __builtin_amdgcn_readlane(hvp[n], kk));
      acc[n] = fdot2f(hb, wp, acc[n]);
    }
  }
#pragma unroll
  for (int n = 0; n < 8; ++n) {
    if (n < ncnt) {
      float part = fmaxf(acc[n], 0.f) * w2v;
      float tot = waveReduceSum(part);
      if (lane == 0) out[base + n] = tot + sarr[wv][n];
    }
  }
}

// ---------------------------------------------------------------------------
extern "C" void kernel_launch(void* const* d_in, const int* in_sizes, int n_in,
                              void* d_out, int out_size, void* d_ws, size_t ws_size,
                              hipStream_t stream) {
  (void)in_sizes; (void)n_in; (void)out_size; (void)ws_size;
  const float* x       = (const float*)d_in[0];
  const int*   ei      = (const int*)d_in[1];
  const int*   hv      = (const int*)d_in[2];
  const int*   he      = (const int*)d_in[3];
  const float* conv1_W = (const float*)d_in[5];
  const float* conv1_b = (const float*)d_in[6];
  const float* conv2_W = (const float*)d_in[7];
  const float* conv2_b = (const float*)d_in[8];
  const float* lin_W   = (const float*)d_in[9];
  const float* lin_b   = (const float*)d_in[10];
  const float* W1      = (const float*)d_in[11];
  const float* b1      = (const float*)d_in[12];
  const float* W2      = (const float*)d_in[13];
  const float* b2      = (const float*)d_in[14];
  const float* Wu      = (const float*)d_in[15];
  const float* bu      = (const float*)d_in[16];
  const float* cls_W   = (const float*)d_in[17];
  const float* cls_b   = (const float*)d_in[18];
  const float* lp_W    = (const float*)d_in[19];
  const float* lp_b    = (const float*)d_in[20];
  const float* head_W  = (const float*)d_in[21];
  const float* head_b  = (const float*)d_in[22];
  const int* src = ei;
  const int* dst = ei + NE;
  float* out = (float*)d_out;

  // workspace layout (float units), fp16 arrays tightly packed (~97 MB total)
  float* H     = (float*)d_ws;              // NN*64 f32   h
  __half* PH   = (__half*)(H + (size_t)NN * 64);        // NN*64 fp16  xw1' then C
  float* Q     = (float*)(PH + (size_t)NN * 64);        // NN*64 f32   A
  __half* XEH  = (__half*)(Q + (size_t)NN * 64);        // NH*64 fp16  B
  float* DINV  = (float*)(XEH + (size_t)NH * 64);       // NN
  float* TP    = DINV + NN;                 // NN   t' = t*dinv
  float* SV    = TP + NN;                   // 192
  int* WUP     = (int*)(SV + 192);          // 2048 packed fp16x2 Wu
  int* W2P     = WUP + 2048;                // 2048 packed fp16x2 W2[64:]
  int* GCUR    = W2P + 2048;                // NBUK
  int* OFFB    = GCUR + NBUK;               // NS
  int* OFFE    = OFFB + NS;                 // NS
  int* ADJ     = OFFE + NS;                 // NBUK*P2CAP (24 MB)

  hipMemsetAsync(GCUR, 0, NBUK * 4, stream);

  k_vecs<<<1, 64, 0, stream>>>(conv2_W, conv2_b, cls_W, cls_b, lp_W, lp_b, head_W, head_b, SV);
  k_pack<<<16, 256, 0, stream>>>(Wu, W2, WUP, W2P);

  // CSR build (strided buckets; no global scan pass)
  k_phase1<<<NWG1, 1024, 0, stream>>>(src, dst, he, hv, GCUR, ADJ);
  k_phase2<<<NBUK, 256, 0, stream>>>(GCUR, ADJ, OFFB, OFFE);
  k_dinv<<<(NN + 255) / 256, 256, 0, stream>>>(OFFB, OFFE, DINV);

  // dense: xw1' = (x @ conv1_W) * dinv[row]  (fp16); h = relu(x @ lin_W + lin_b) (f32)
  k_gemm<128, false, false, true, __half><<<2048, 256, 0, stream>>>(x, conv1_W, nullptr, DINV, PH, NN);
  k_gemm<128, true, true, false, float><<<2048, 256, 0, stream>>>(x, lin_W, lin_b, nullptr, H, NN);

  // GCN branch collapsed to t' (conv2 folded into k_final)
  k_gcn1_gather<<<NN / 4, 256, 0, stream>>>(OFFB, OFFE, ADJ, PH, DINV, conv1_b, SV, TP);

  // hyper branch dense parts: A = h @ W2[:64] (f32, Q); C = h @ W1 + b1 (fp16, PH)
  k_gemm<64, false, false, false, float><<<2048, 256, 0, stream>>>(H, W2, nullptr, nullptr, Q, NN);
  k_gemm<64, true, false, false, __half><<<2048, 256, 0, stream>>>(H, W1, b1, nullptr, PH, NN);

  // 4 hyperedges per wave -> 3125 blocks
  k_xe_gather<<<3125, 256, 0, stream>>>(OFFB, OFFE, ADJ, PH, W2P, b2, XEH);

  // 8 nodes per wave -> 3125 blocks
  k_final<<<3125, 256, 0, stream>>>(OFFB, OFFE, ADJ, Q, XEH, H, TP, DINV, WUP, bu, SV, out);
}

// Round 16
// 374.985 us; speedup vs baseline: 1.9206x; 1.0010x over previous
//
#include <hip/hip_runtime.h>
#include <hip/hip_fp16.h>

#define NN 100000   // nodes
#define NF 128      // input features
#define D  64       // hidden dim
#define NE 1600000  // edges
#define NZ 1000000  // hypergraph incidences
#define NH 50000    // hyperedges

#define NS (NN + NH + NN)          // 250000 concatenated id space
#define TOT (NE + 2 * NZ)          // 3600000 adjacency entries
#define NBUK 977                   // ceil(NS/256) buckets of 256 ids
#define NWG1 256                   // phase-1 workgroups
#define P2CAP 6144                 // bucket stride/capacity

typedef _Float16 half2v __attribute__((ext_vector_type(2)));

static __device__ __forceinline__ float waveReduceSum(float v) {
#pragma unroll
  for (int off = 32; off > 0; off >>= 1) v += __shfl_down(v, off);
  return v;
}

// Wave-uniform broadcast via readlane (VALU pipe, not ds_bpermute/LDS pipe).
static __device__ __forceinline__ float bcastf(float v, int l) {
  return __int_as_float(__builtin_amdgcn_readlane(__float_as_int(v), l));
}

#if __has_builtin(__builtin_amdgcn_fdot2)
static __device__ __forceinline__ float fdot2f(half2v a, half2v b, float c) {
  return __builtin_amdgcn_fdot2(a, b, c, false);
}
#else
static __device__ __forceinline__ float fdot2f(half2v a, half2v b, float c) {
  return fmaf((float)a.x, (float)b.x, fmaf((float)a.y, (float)b.y, c));
}
#endif

// ---------------------------------------------------------------------------
// sv[0:64)   u    = conv2_W @ v1          (v1 = lp_W[:64] @ head_W)
// sv[64:128) w2v  = cls_W  @ v2           (v2 = lp_W[64:] @ head_W)
// sv[128]    c_all= lp_b.head_W + head_b + conv2_b.v1 + cls_b.v2
// ---------------------------------------------------------------------------
__global__ void k_vecs(const float* __restrict__ conv2_W, const float* __restrict__ conv2_b,
                       const float* __restrict__ cls_W, const float* __restrict__ cls_b,
                       const float* __restrict__ lp_W, const float* __restrict__ lp_b,
                       const float* __restrict__ head_W, const float* __restrict__ head_b,
                       float* __restrict__ sv) {
  int t = threadIdx.x;  // 0..63, one wave
  __shared__ float v1[64], v2[64];
  float a1 = 0.f, a2 = 0.f;
  for (int c = 0; c < 64; ++c) {
    float hw = head_W[c];
    a1 = fmaf(lp_W[t * 64 + c], hw, a1);
    a2 = fmaf(lp_W[(64 + t) * 64 + c], hw, a2);
  }
  v1[t] = a1;
  v2[t] = a2;
  __syncthreads();
  float u = 0.f, w = 0.f;
  for (int c = 0; c < 64; ++c) {
    u = fmaf(conv2_W[t * 64 + c], v1[c], u);
    w = fmaf(cls_W[t * 64 + c], v2[c], w);
  }
  sv[t] = u;
  sv[64 + t] = w;
  float part = lp_b[t] * head_W[t] + conv2_b[t] * v1[t] + cls_b[t] * v2[t];
  part = waveReduceSum(part);
  if (t == 0) sv[128] = part + head_b[0];
}

// ---------------------------------------------------------------------------
// Pack Wu and W2[64:128] rows pairwise into fp16x2 tables for fdot2 matvec.
// ---------------------------------------------------------------------------
__global__ void k_pack(const float* __restrict__ Wu, const float* __restrict__ W2,
                       int* __restrict__ WUP, int* __restrict__ W2P) {
  int t = blockIdx.x * 256 + threadIdx.x;
  if (t < 2048) {
    int kk = t >> 6, lane = t & 63;
    half2v p;
    p.x = (_Float16)Wu[(2 * kk) * 64 + lane];
    p.y = (_Float16)Wu[(2 * kk + 1) * 64 + lane];
    WUP[t] = __builtin_bit_cast(int, p);
  } else if (t < 4096) {
    int u = t - 2048;
    int kk = u >> 6, lane = u & 63;
    half2v p;
    p.x = (_Float16)W2[(64 + 2 * kk) * 64 + lane];
    p.y = (_Float16)W2[(64 + 2 * kk + 1) * 64 + lane];
    W2P[u] = __builtin_bit_cast(int, p);
  }
}

// ---------------------------------------------------------------------------
// Tall-skinny GEMM: out[r,c] = scale?*(act(in[r,:K] @ W[K,64] + b[c]))
// readlane broadcast (VALU) + next-row prefetch.  [R7-proven]
// IT/OT = float or __half.
// ---------------------------------------------------------------------------
template <int K, bool BIAS, bool RELU, bool SCALE, typename IT, typename OT>
__global__ __launch_bounds__(256) void k_gemm(const IT* __restrict__ in,
                                              const float* __restrict__ W,
                                              const float* __restrict__ bias,
                                              const float* __restrict__ scale,
                                              OT* __restrict__ out, int nrows) {
  int lane = threadIdx.x & 63;
  int wave = threadIdx.x >> 6;
  float w[K];
#pragma unroll
  for (int k = 0; k < K; ++k) w[k] = W[k * 64 + lane];
  float b = BIAS ? bias[lane] : 0.0f;
  int wid = blockIdx.x * 4 + wave;
  int nw = gridDim.x * 4;
  if (wid >= nrows) return;
  float v0 = (float)in[(size_t)wid * K + lane];
  float v1 = 0.f;
  if constexpr (K == 128) v1 = (float)in[(size_t)wid * K + 64 + lane];
  for (int row = wid; row < nrows; row += nw) {
    int nrow = row + nw;
    float nv0 = 0.f, nv1 = 0.f;
    if (nrow < nrows) {
      nv0 = (float)in[(size_t)nrow * K + lane];
      if constexpr (K == 128) nv1 = (float)in[(size_t)nrow * K + 64 + lane];
    }
    float acc0 = b, acc1 = 0.f;
#pragma unroll
    for (int k = 0; k < 64; k += 2) {
      acc0 = fmaf(bcastf(v0, k), w[k], acc0);
      acc1 = fmaf(bcastf(v0, k + 1), w[k + 1], acc1);
    }
    if constexpr (K == 128) {
#pragma unroll
      for (int k = 0; k < 64; k += 2) {
        acc0 = fmaf(bcastf(v1, k), w[64 + k], acc0);
        acc1 = fmaf(bcastf(v1, k + 1), w[64 + k + 1], acc1);
      }
    }
    float r = acc0 + acc1;
    if (RELU) r = fmaxf(r, 0.0f);
    if (SCALE) r *= scale[row];
    out[(size_t)row * 64 + lane] = (OT)r;
    v0 = nv0;
    v1 = nv1;
  }
}

// ---------------------------------------------------------------------------
// Fused dual GEMM over h (fp16): C = h@W1 + b1 (fp16), A = h@W2[:64] (fp16).
// Reads h ONCE. Weight footprint = 128 VGPR (same as proven K=128 GEMM).
// ---------------------------------------------------------------------------
__global__ __launch_bounds__(256) void k_gemm_dual(const __half* __restrict__ in,
                                                   const float* __restrict__ W1,
                                                   const float* __restrict__ b1,
                                                   const float* __restrict__ W2,
                                                   __half* __restrict__ Cout,
                                                   __half* __restrict__ Aout, int nrows) {
  int lane = threadIdx.x & 63;
  int wave = threadIdx.x >> 6;
  float w1[64], w2[64];
#pragma unroll
  for (int k = 0; k < 64; ++k) {
    w1[k] = W1[k * 64 + lane];
    w2[k] = W2[k * 64 + lane];
  }
  float bb = b1[lane];
  int wid = blockIdx.x * 4 + wave;
  int nw = gridDim.x * 4;
  if (wid >= nrows) return;
  float v0 = (float)in[(size_t)wid * 64 + lane];
  for (int row = wid; row < nrows; row += nw) {
    int nrow = row + nw;
    float nv0 = (nrow < nrows) ? (float)in[(size_t)nrow * 64 + lane] : 0.f;
    float accC = bb, accA = 0.f;
#pragma unroll
    for (int k = 0; k < 64; ++k) {
      float f = bcastf(v0, k);
      accC = fmaf(f, w1[k], accC);
      accA = fmaf(f, w2[k], accA);
    }
    Cout[(size_t)row * 64 + lane] = (__half)accC;
    Aout[(size_t)row * 64 + lane] = (__half)accA;
    v0 = nv0;
  }
}

// ---------------------------------------------------------------------------
// CSR build (no global scan): fixed-stride buckets at b*P2CAP.
// ---------------------------------------------------------------------------
__global__ __launch_bounds__(1024) void k_phase1(const int* __restrict__ src,
                                                 const int* __restrict__ dst,
                                                 const int* __restrict__ he,
                                                 const int* __restrict__ hv,
                                                 int* __restrict__ gcur,
                                                 int* __restrict__ adj) {
  __shared__ int cnt[NBUK], base[NBUK], cur[NBUK];
  int tid = threadIdx.x;
  for (int b = tid; b < NBUK; b += 1024) { cnt[b] = 0; cur[b] = 0; }
  __syncthreads();
  int per = (TOT + NWG1 - 1) / NWG1;
  int s0 = blockIdx.x * per;
  int s1 = s0 + per; if (s1 > TOT) s1 = TOT;
  for (int j = s0 + tid; j < s1; j += 1024) {
    int id;
    if (j < NE) id = dst[j];
    else if (j < NE + NZ) id = NN + he[j - NE];
    else id = NN + NH + hv[j - NE - NZ];
    atomicAdd(&cnt[id >> 8], 1);
  }
  __syncthreads();
  for (int b = tid; b < NBUK; b += 1024) {
    int c = cnt[b];
    if (c) base[b] = b * P2CAP + atomicAdd(&gcur[b], c);
  }
  __syncthreads();
  for (int j = s0 + tid; j < s1; j += 1024) {
    int id, val;
    if (j < NE)           { id = dst[j];                val = src[j]; }
    else if (j < NE + NZ) { id = NN + he[j - NE];       val = hv[j - NE]; }
    else                  { id = NN + NH + hv[j - NE - NZ]; val = he[j - NE - NZ]; }
    int b = id >> 8;
    int slot = base[b] + atomicAdd(&cur[b], 1);
    adj[slot] = ((id & 255) << 17) | val;   // val < 131072
  }
}

__global__ __launch_bounds__(256) void k_phase2(const int* __restrict__ gcur,
                                                int* __restrict__ adj,
                                                int* __restrict__ offb,
                                                int* __restrict__ offe) {
  __shared__ int ent[P2CAP];
  __shared__ int hist[256];
  int b = blockIdx.x, tid = threadIdx.x;
  int s = b * P2CAP;
  int n = gcur[b];
  if (n > P2CAP) n = P2CAP;  // safety; cannot trigger on this dataset
  hist[tid] = 0;
  __syncthreads();
  for (int k = tid; k < n; k += 256) {
    int v = adj[s + k];
    ent[k] = v;
    atomicAdd(&hist[v >> 17], 1);
  }
  __syncthreads();
  int c = hist[tid];
#pragma unroll
  for (int d = 1; d < 256; d <<= 1) {
    int x = (tid >= d) ? hist[tid - d] : 0;
    __syncthreads();
    hist[tid] += x;
    __syncthreads();
  }
  int excl = hist[tid] - c;
  hist[tid] = excl;
  int gid = (b << 8) + tid;
  if (gid < NS) {
    offb[gid] = s + excl;
    offe[gid] = s + excl + c;
  }
  __syncthreads();
  for (int k = tid; k < n; k += 256) {
    int v = ent[k];
    int pos = atomicAdd(&hist[v >> 17], 1);
    adj[s + pos] = v & 0x1FFFF;   // store bare value
  }
}

__global__ void k_dinv(const int* __restrict__ offb, const int* __restrict__ offe,
                       float* __restrict__ dinv) {
  int i = blockIdx.x * 256 + threadIdx.x;
  if (i < NN) dinv[i] = rsqrtf((float)(offe[i] - offb[i] + 1));  // +1 self-loop
}

// ---------------------------------------------------------------------------
// Predicated batched row-gather (8 in flight); ROWS may be float* or __half*.
// Uses `beg`, `end`, `adj`, `lane` from enclosing scope.  [R10-proven]
// ---------------------------------------------------------------------------
#define GATHER_ROWS8(ROWS, ACCUM_STMT)                                  \
  for (int j0 = beg; j0 < end; j0 += 64) {                              \
    int m = end - j0; if (m > 64) m = 64;                               \
    int a = (lane < m) ? adj[j0 + lane] : 0;                            \
    for (int k = 0; k < m; k += 8) {                                    \
      int s_[8]; float r_[8];                                           \
      _Pragma("unroll")                                                 \
      for (int q = 0; q < 8; ++q) {                                     \
        int kk = k + q; kk = (kk < m - 1) ? kk : (m - 1);               \
        s_[q] = __shfl(a, kk);                                          \
      }                                                                 \
      _Pragma("unroll")                                                 \
      for (int q = 0; q < 8; ++q) r_[q] = (float)ROWS[(size_t)s_[q] * 64 + lane]; \
      _Pragma("unroll")                                                 \
      for (int q = 0; q < 8; ++q) {                                     \
        if (k + q < m) { ACCUM_STMT(r_[q]); }                           \
      }                                                                 \
    }                                                                   \
  }

// ---------------------------------------------------------------------------
// conv1 gather over fp16 xw1p (pre-scaled by dinv[row]):
//   t'[i] = dinv[i] * ( relu( dinv[i]*(sum_s xw1p[s] + xw1p[i]) + conv1_b ) . u )
// ---------------------------------------------------------------------------
__global__ __launch_bounds__(256) void k_gcn1_gather(const int* __restrict__ offb,
                                                     const int* __restrict__ offe,
                                                     const int* __restrict__ adj,
                                                     const __half* __restrict__ xw1p,
                                                     const float* __restrict__ dinv,
                                                     const float* __restrict__ conv1_b,
                                                     const float* __restrict__ sv,
                                                     float* __restrict__ tp) {
  int i = blockIdx.x * 4 + (threadIdx.x >> 6);
  if (i >= NN) return;
  int lane = threadIdx.x & 63;
  int beg = offb[i], end = offe[i];
  float acc = 0.f;
#define ACC_ADD(r) acc += (r)
  GATHER_ROWS8(xw1p, ACC_ADD)
#undef ACC_ADD
  float di = dinv[i];
  float selfv = (float)xw1p[(size_t)i * 64 + lane];
  float r = fmaxf(fmaf(acc + selfv, di, conv1_b[lane]), 0.f);
  float p = waveReduceSum(r * sv[lane]);
  if (lane == 0) tp[i] = p * di;
}

// ---------------------------------------------------------------------------
// Xe gather + batched matvec. 4 hyperedges/wave, grid 3125.  [R15-proven]
// ---------------------------------------------------------------------------
__global__ __launch_bounds__(256) void k_xe_gather(const int* __restrict__ offb,
                                                   const int* __restrict__ offe,
                                                   const int* __restrict__ adj,
                                                   const __half* __restrict__ C,
                                                   const int* __restrict__ W2P,
                                                   const float* __restrict__ b2,
                                                   __half* __restrict__ B) {
  __shared__ float hp[4][4][64];
  int lane = threadIdx.x & 63, wv = threadIdx.x >> 6;
  int base = (blockIdx.x * 4 + wv) * 4;
  if (base >= NH) return;
  int ncnt = NH - base; if (ncnt > 4) ncnt = 4;
  for (int n = 0; n < ncnt; ++n) {
    int e = base + n;
    int beg = offb[NN + e], end = offe[NN + e];
    float acc = 0.f;
#define ACC_ADD(r) acc += (r)
    GATHER_ROWS8(C, ACC_ADD)
#undef ACC_ADD
    hp[wv][n][lane] = acc / fmaxf((float)(end - beg), 1.0f);
  }
  int l2 = lane & 31;
  int hvp[4];
#pragma unroll
  for (int n = 0; n < 4; ++n) {
    half2v p;
    p.x = (_Float16)hp[wv][n][2 * l2];
    p.y = (_Float16)hp[wv][n][2 * l2 + 1];
    hvp[n] = __builtin_bit_cast(int, p);
  }
  float bb = b2[lane];
  float acc[4];
#pragma unroll
  for (int n = 0; n < 4; ++n) acc[n] = bb;
  for (int kk = 0; kk < 32; ++kk) {
    half2v wp = __builtin_bit_cast(half2v, W2P[kk * 64 + lane]);
#pragma unroll
    for (int n = 0; n < 4; ++n) {
      half2v hb = __builtin_bit_cast(half2v, __builtin_amdgcn_readlane(hvp[n], kk));
      acc[n] = fdot2f(hb, wp, acc[n]);
    }
  }
#pragma unroll
  for (int n = 0; n < 4; ++n)
    if (n < ncnt) B[(size_t)(base + n) * 64 + lane] = (__half)acc[n];
}

// ---------------------------------------------------------------------------
// Final fused kernel. 8 nodes/wave, grid 3125.  [R15 structure; fp16 streams]
// ---------------------------------------------------------------------------
__global__ __launch_bounds__(256) void k_final(const int* __restrict__ offb,
                                               const int* __restrict__ offe,
                                               const int* __restrict__ adj,
                                               const __half* __restrict__ A,
                                               const __half* __restrict__ B,
                                               const __half* __restrict__ h,
                                               const float* __restrict__ tp,
                                               const float* __restrict__ dinv,
                                               const int* __restrict__ WUP,
                                               const float* __restrict__ bu,
                                               const float* __restrict__ sv,
                                               float* __restrict__ out) {
  __shared__ float hp[4][8][64];
  __shared__ float sarr[4][8];
  int lane = threadIdx.x & 63, wv = threadIdx.x >> 6;
  int base = (blockIdx.x * 4 + wv) * 8;
  if (base >= NN) return;
  int ncnt = NN - base; if (ncnt > 8) ncnt = 8;
  float c_all = sv[128];
  for (int n = 0; n < ncnt; ++n) {
    int i = base + n;
    float av = (float)A[(size_t)i * 64 + lane];
    int beg = offb[NN + NH + i], end = offe[NN + NH + i];
    float accm = 0.f;
#define ACC_RELU(r) accm += fmaxf(av + (r), 0.f)
    GATHER_ROWS8(B, ACC_RELU)
#undef ACC_RELU
    hp[wv][n][lane] = accm * (0.5f / fmaxf((float)(end - beg), 1.0f)) +
                      0.5f * (float)h[(size_t)i * 64 + lane];
    // gcn2 scalar gather over dst-CSR
    float di = dinv[i];
    int db = offb[i], de = offe[i];
    float g = 0.f;
    for (int j = db + lane; j < de; j += 64) g += tp[adj[j]];
    float gr = waveReduceSum(g);
    if (lane == 0) sarr[wv][n] = gr * di + tp[i] * di + c_all;
  }
  int l2 = lane & 31;
  int hvp[8];
#pragma unroll
  for (int n = 0; n < 8; ++n) {
    half2v p;
    p.x = (_Float16)hp[wv][n][2 * l2];
    p.y = (_Float16)hp[wv][n][2 * l2 + 1];
    hvp[n] = __builtin_bit_cast(int, p);
  }
  float bb = bu[lane];
  float w2v = sv[64 + lane];
  float acc[8];
#pragma unroll
  for (int n = 0; n < 8; ++n) acc[n] = bb;
  for (int kk = 0; kk < 32; ++kk) {
    half2v wp = __builtin_bit_cast(half2v, WUP[kk * 64 + lane]);
#pragma unroll
    for (int n = 0; n < 8; ++n) {
      half2v hb = __builtin_bit_cast(half2v, __builtin_amdgcn_readlane(hvp[n], kk));
      acc[n] = fdot2f(hb, wp, acc[n]);
    }
  }
#pragma unroll
  for (int n = 0; n < 8; ++n) {
    if (n < ncnt) {
      float part = fmaxf(acc[n], 0.f) * w2v;
      float tot = waveReduceSum(part);
      if (lane == 0) out[base + n] = tot + sarr[wv][n];
    }
  }
}

// ---------------------------------------------------------------------------
extern "C" void kernel_launch(void* const* d_in, const int* in_sizes, int n_in,
                              void* d_out, int out_size, void* d_ws, size_t ws_size,
                              hipStream_t stream) {
  (void)in_sizes; (void)n_in; (void)out_size; (void)ws_size;
  const float* x       = (const float*)d_in[0];
  const int*   ei      = (const int*)d_in[1];
  const int*   hv      = (const int*)d_in[2];
  const int*   he      = (const int*)d_in[3];
  const float* conv1_W = (const float*)d_in[5];
  const float* conv1_b = (const float*)d_in[6];
  const float* conv2_W = (const float*)d_in[7];
  const float* conv2_b = (const float*)d_in[8];
  const float* lin_W   = (const float*)d_in[9];
  const float* lin_b   = (const float*)d_in[10];
  const float* W1      = (const float*)d_in[11];
  const float* b1      = (const float*)d_in[12];
  const float* W2      = (const float*)d_in[13];
  const float* b2      = (const float*)d_in[14];
  const float* Wu      = (const float*)d_in[15];
  const float* bu      = (const float*)d_in[16];
  const float* cls_W   = (const float*)d_in[17];
  const float* cls_b   = (const float*)d_in[18];
  const float* lp_W    = (const float*)d_in[19];
  const float* lp_b    = (const float*)d_in[20];
  const float* head_W  = (const float*)d_in[21];
  const float* head_b  = (const float*)d_in[22];
  const int* src = ei;
  const int* dst = ei + NE;
  float* out = (float*)d_out;

  // workspace layout: all intermediate N*64 streams fp16 (~60 MB total)
  __half* H16  = (__half*)d_ws;                         // NN*64 fp16  h
  __half* PH   = H16 + (size_t)NN * 64;                 // NN*64 fp16  xw1' then C
  __half* QH   = PH + (size_t)NN * 64;                  // NN*64 fp16  A
  __half* XEH  = QH + (size_t)NN * 64;                  // NH*64 fp16  B
  float* DINV  = (float*)(XEH + (size_t)NH * 64);       // NN
  float* TP    = DINV + NN;                 // NN   t' = t*dinv
  float* SV    = TP + NN;                   // 192
  int* WUP     = (int*)(SV + 192);          // 2048 packed fp16x2 Wu
  int* W2P     = WUP + 2048;                // 2048 packed fp16x2 W2[64:]
  int* GCUR    = W2P + 2048;                // NBUK
  int* OFFB    = GCUR + NBUK;               // NS
  int* OFFE    = OFFB + NS;                 // NS
  int* ADJ     = OFFE + NS;                 // NBUK*P2CAP (24 MB)

  hipMemsetAsync(GCUR, 0, NBUK * 4, stream);

  k_vecs<<<1, 64, 0, stream>>>(conv2_W, conv2_b, cls_W, cls_b, lp_W, lp_b, head_W, head_b, SV);
  k_pack<<<16, 256, 0, stream>>>(Wu, W2, WUP, W2P);

  // CSR build (strided buckets; no global scan pass)
  k_phase1<<<NWG1, 1024, 0, stream>>>(src, dst, he, hv, GCUR, ADJ);
  k_phase2<<<NBUK, 256, 0, stream>>>(GCUR, ADJ, OFFB, OFFE);
  k_dinv<<<(NN + 255) / 256, 256, 0, stream>>>(OFFB, OFFE, DINV);

  // dense: xw1' = (x @ conv1_W) * dinv[row]  (fp16); h = relu(x @ lin_W + lin_b) (fp16)
  k_gemm<128, false, false, true, float, __half><<<2048, 256, 0, stream>>>(x, conv1_W, nullptr, DINV, PH, NN);
  k_gemm<128, true, true, false, float, __half><<<2048, 256, 0, stream>>>(x, lin_W, lin_b, nullptr, H16, NN);

  // GCN branch collapsed to t' (conv2 folded into k_final)
  k_gcn1_gather<<<NN / 4, 256, 0, stream>>>(OFFB, OFFE, ADJ, PH, DINV, conv1_b, SV, TP);

  // hyper branch dense parts fused: C = h@W1+b1 (PH), A = h@W2[:64] (QH)
  k_gemm_dual<<<2048, 256, 0, stream>>>(H16, W1, b1, W2, PH, QH, NN);

  // 4 hyperedges per wave -> 3125 blocks
  k_xe_gather<<<3125, 256, 0, stream>>>(OFFB, OFFE, ADJ, PH, W2P, b2, XEH);

  // 8 nodes per wave -> 3125 blocks
  k_final<<<3125, 256, 0, stream>>>(OFFB, OFFE, ADJ, QH, XEH, H16, TP, DINV, WUP, bu, SV, out);
}

// Round 17
// 357.871 us; speedup vs baseline: 2.0125x; 1.0478x over previous
//
#include <hip/hip_runtime.h>
#include <hip/hip_fp16.h>

#define NN 100000   // nodes
#define NF 128      // input features
#define D  64       // hidden dim
#define NE 1600000  // edges
#define NZ 1000000  // hypergraph incidences
#define NH 50000    // hyperedges

#define NS (NN + NH + NN)          // 250000 concatenated id space
#define TOT (NE + 2 * NZ)          // 3600000 adjacency entries
#define NBUK 977                   // ceil(NS/256) buckets of 256 ids
#define NWG1 256                   // phase-1 workgroups
#define P2CAP 6144                 // bucket stride/capacity

typedef _Float16 half2v __attribute__((ext_vector_type(2)));

static __device__ __forceinline__ float waveReduceSum(float v) {
#pragma unroll
  for (int off = 32; off > 0; off >>= 1) v += __shfl_down(v, off);
  return v;
}

// Wave-uniform broadcast via readlane (VALU pipe, not ds_bpermute/LDS pipe).
static __device__ __forceinline__ float bcastf(float v, int l) {
  return __int_as_float(__builtin_amdgcn_readlane(__float_as_int(v), l));
}

#if __has_builtin(__builtin_amdgcn_fdot2)
static __device__ __forceinline__ float fdot2f(half2v a, half2v b, float c) {
  return __builtin_amdgcn_fdot2(a, b, c, false);
}
#else
static __device__ __forceinline__ float fdot2f(half2v a, half2v b, float c) {
  return fmaf((float)a.x, (float)b.x, fmaf((float)a.y, (float)b.y, c));
}
#endif

// ---------------------------------------------------------------------------
// sv[0:64)   u    = conv2_W @ v1          (v1 = lp_W[:64] @ head_W)
// sv[64:128) w2v  = cls_W  @ v2           (v2 = lp_W[64:] @ head_W)
// sv[128]    c_all= lp_b.head_W + head_b + conv2_b.v1 + cls_b.v2
// ---------------------------------------------------------------------------
__global__ void k_vecs(const float* __restrict__ conv2_W, const float* __restrict__ conv2_b,
                       const float* __restrict__ cls_W, const float* __restrict__ cls_b,
                       const float* __restrict__ lp_W, const float* __restrict__ lp_b,
                       const float* __restrict__ head_W, const float* __restrict__ head_b,
                       float* __restrict__ sv) {
  int t = threadIdx.x;  // 0..63, one wave
  __shared__ float v1[64], v2[64];
  float a1 = 0.f, a2 = 0.f;
  for (int c = 0; c < 64; ++c) {
    float hw = head_W[c];
    a1 = fmaf(lp_W[t * 64 + c], hw, a1);
    a2 = fmaf(lp_W[(64 + t) * 64 + c], hw, a2);
  }
  v1[t] = a1;
  v2[t] = a2;
  __syncthreads();
  float u = 0.f, w = 0.f;
  for (int c = 0; c < 64; ++c) {
    u = fmaf(conv2_W[t * 64 + c], v1[c], u);
    w = fmaf(cls_W[t * 64 + c], v2[c], w);
  }
  sv[t] = u;
  sv[64 + t] = w;
  float part = lp_b[t] * head_W[t] + conv2_b[t] * v1[t] + cls_b[t] * v2[t];
  part = waveReduceSum(part);
  if (t == 0) sv[128] = part + head_b[0];
}

// ---------------------------------------------------------------------------
// Pack Wu and W2[64:128] rows pairwise into fp16x2 tables for fdot2 matvec.
// ---------------------------------------------------------------------------
__global__ void k_pack(const float* __restrict__ Wu, const float* __restrict__ W2,
                       int* __restrict__ WUP, int* __restrict__ W2P) {
  int t = blockIdx.x * 256 + threadIdx.x;
  if (t < 2048) {
    int kk = t >> 6, lane = t & 63;
    half2v p;
    p.x = (_Float16)Wu[(2 * kk) * 64 + lane];
    p.y = (_Float16)Wu[(2 * kk + 1) * 64 + lane];
    WUP[t] = __builtin_bit_cast(int, p);
  } else if (t < 4096) {
    int u = t - 2048;
    int kk = u >> 6, lane = u & 63;
    half2v p;
    p.x = (_Float16)W2[(64 + 2 * kk) * 64 + lane];
    p.y = (_Float16)W2[(64 + 2 * kk + 1) * 64 + lane];
    W2P[u] = __builtin_bit_cast(int, p);
  }
}

// ---------------------------------------------------------------------------
// Tall-skinny GEMM: out[r,c] = scale?*(act(in[r,:K] @ W[K,64] + b[c]))
// readlane broadcast (VALU) + next-row prefetch.  [R7-proven]
// ---------------------------------------------------------------------------
template <int K, bool BIAS, bool RELU, bool SCALE, typename IT, typename OT>
__global__ __launch_bounds__(256) void k_gemm(const IT* __restrict__ in,
                                              const float* __restrict__ W,
                                              const float* __restrict__ bias,
                                              const float* __restrict__ scale,
                                              OT* __restrict__ out, int nrows) {
  int lane = threadIdx.x & 63;
  int wave = threadIdx.x >> 6;
  float w[K];
#pragma unroll
  for (int k = 0; k < K; ++k) w[k] = W[k * 64 + lane];
  float b = BIAS ? bias[lane] : 0.0f;
  int wid = blockIdx.x * 4 + wave;
  int nw = gridDim.x * 4;
  if (wid >= nrows) return;
  float v0 = (float)in[(size_t)wid * K + lane];
  float v1 = 0.f;
  if constexpr (K == 128) v1 = (float)in[(size_t)wid * K + 64 + lane];
  for (int row = wid; row < nrows; row += nw) {
    int nrow = row + nw;
    float nv0 = 0.f, nv1 = 0.f;
    if (nrow < nrows) {
      nv0 = (float)in[(size_t)nrow * K + lane];
      if constexpr (K == 128) nv1 = (float)in[(size_t)nrow * K + 64 + lane];
    }
    float acc0 = b, acc1 = 0.f;
#pragma unroll
    for (int k = 0; k < 64; k += 2) {
      acc0 = fmaf(bcastf(v0, k), w[k], acc0);
      acc1 = fmaf(bcastf(v0, k + 1), w[k + 1], acc1);
    }
    if constexpr (K == 128) {
#pragma unroll
      for (int k = 0; k < 64; k += 2) {
        acc0 = fmaf(bcastf(v1, k), w[64 + k], acc0);
        acc1 = fmaf(bcastf(v1, k + 1), w[64 + k + 1], acc1);
      }
    }
    float r = acc0 + acc1;
    if (RELU) r = fmaxf(r, 0.0f);
    if (SCALE) r *= scale[row];
    out[(size_t)row * 64 + lane] = (OT)r;
    v0 = nv0;
    v1 = nv1;
  }
}

// ---------------------------------------------------------------------------
// Fused dual GEMM over h (fp16): C = h@W1 + b1 (fp16), A = h@W2[:64] (fp16).
// ---------------------------------------------------------------------------
__global__ __launch_bounds__(256) void k_gemm_dual(const __half* __restrict__ in,
                                                   const float* __restrict__ W1,
                                                   const float* __restrict__ b1,
                                                   const float* __restrict__ W2,
                                                   __half* __restrict__ Cout,
                                                   __half* __restrict__ Aout, int nrows) {
  int lane = threadIdx.x & 63;
  int wave = threadIdx.x >> 6;
  float w1[64], w2[64];
#pragma unroll
  for (int k = 0; k < 64; ++k) {
    w1[k] = W1[k * 64 + lane];
    w2[k] = W2[k * 64 + lane];
  }
  float bb = b1[lane];
  int wid = blockIdx.x * 4 + wave;
  int nw = gridDim.x * 4;
  if (wid >= nrows) return;
  float v0 = (float)in[(size_t)wid * 64 + lane];
  for (int row = wid; row < nrows; row += nw) {
    int nrow = row + nw;
    float nv0 = (nrow < nrows) ? (float)in[(size_t)nrow * 64 + lane] : 0.f;
    float accC = bb, accA = 0.f;
#pragma unroll
    for (int k = 0; k < 64; ++k) {
      float f = bcastf(v0, k);
      accC = fmaf(f, w1[k], accC);
      accA = fmaf(f, w2[k], accA);
    }
    Cout[(size_t)row * 64 + lane] = (__half)accC;
    Aout[(size_t)row * 64 + lane] = (__half)accA;
    v0 = nv0;
  }
}

// ---------------------------------------------------------------------------
// CSR build (no global scan): fixed-stride buckets at b*P2CAP.
// ---------------------------------------------------------------------------
__global__ __launch_bounds__(1024) void k_phase1(const int* __restrict__ src,
                                                 const int* __restrict__ dst,
                                                 const int* __restrict__ he,
                                                 const int* __restrict__ hv,
                                                 int* __restrict__ gcur,
                                                 int* __restrict__ adj) {
  __shared__ int cnt[NBUK], base[NBUK], cur[NBUK];
  int tid = threadIdx.x;
  for (int b = tid; b < NBUK; b += 1024) { cnt[b] = 0; cur[b] = 0; }
  __syncthreads();
  int per = (TOT + NWG1 - 1) / NWG1;
  int s0 = blockIdx.x * per;
  int s1 = s0 + per; if (s1 > TOT) s1 = TOT;
  for (int j = s0 + tid; j < s1; j += 1024) {
    int id;
    if (j < NE) id = dst[j];
    else if (j < NE + NZ) id = NN + he[j - NE];
    else id = NN + NH + hv[j - NE - NZ];
    atomicAdd(&cnt[id >> 8], 1);
  }
  __syncthreads();
  for (int b = tid; b < NBUK; b += 1024) {
    int c = cnt[b];
    if (c) base[b] = b * P2CAP + atomicAdd(&gcur[b], c);
  }
  __syncthreads();
  for (int j = s0 + tid; j < s1; j += 1024) {
    int id, val;
    if (j < NE)           { id = dst[j];                val = src[j]; }
    else if (j < NE + NZ) { id = NN + he[j - NE];       val = hv[j - NE]; }
    else                  { id = NN + NH + hv[j - NE - NZ]; val = he[j - NE - NZ]; }
    int b = id >> 8;
    int slot = base[b] + atomicAdd(&cur[b], 1);
    adj[slot] = ((id & 255) << 17) | val;   // val < 131072
  }
}

__global__ __launch_bounds__(256) void k_phase2(const int* __restrict__ gcur,
                                                int* __restrict__ adj,
                                                int* __restrict__ offb,
                                                int* __restrict__ offe) {
  __shared__ int ent[P2CAP];
  __shared__ int hist[256];
  int b = blockIdx.x, tid = threadIdx.x;
  int s = b * P2CAP;
  int n = gcur[b];
  if (n > P2CAP) n = P2CAP;  // safety; cannot trigger on this dataset
  hist[tid] = 0;
  __syncthreads();
  for (int k = tid; k < n; k += 256) {
    int v = adj[s + k];
    ent[k] = v;
    atomicAdd(&hist[v >> 17], 1);
  }
  __syncthreads();
  int c = hist[tid];
#pragma unroll
  for (int d = 1; d < 256; d <<= 1) {
    int x = (tid >= d) ? hist[tid - d] : 0;
    __syncthreads();
    hist[tid] += x;
    __syncthreads();
  }
  int excl = hist[tid] - c;
  hist[tid] = excl;
  int gid = (b << 8) + tid;
  if (gid < NS) {
    offb[gid] = s + excl;
    offe[gid] = s + excl + c;
  }
  __syncthreads();
  for (int k = tid; k < n; k += 256) {
    int v = ent[k];
    int pos = atomicAdd(&hist[v >> 17], 1);
    adj[s + pos] = v & 0x1FFFF;   // store bare value
  }
}

__global__ void k_dinv(const int* __restrict__ offb, const int* __restrict__ offe,
                       float* __restrict__ dinv) {
  int i = blockIdx.x * 256 + threadIdx.x;
  if (i < NN) dinv[i] = rsqrtf((float)(offe[i] - offb[i] + 1));  // +1 self-loop
}

// ---------------------------------------------------------------------------
// Packed-fp16 gather: 64 lanes = 32 col-pairs (c) x 2 element-slots (eo).
// Per 16-element batch: 8 shfl + 8 half2 loads + 8 (cndmask + pk ops).
// ACCUM2(r_q, ok) accumulates into half2 b2; flushed to f32 ax/ay per batch.
// ---------------------------------------------------------------------------
#define GATHER_PK16(ROWS2, PKBODY)                                      \
  for (int j0 = beg; j0 < end; j0 += 64) {                              \
    int m = end - j0; if (m > 64) m = 64;                               \
    int a = (lane < m) ? adj[j0 + lane] : 0;                            \
    for (int k = 0; k < m; k += 16) {                                   \
      int s_[8]; half2v r_[8];                                          \
      _Pragma("unroll")                                                 \
      for (int q = 0; q < 8; ++q) {                                     \
        int kk = k + 2 * q + eo;                                        \
        int kc = (kk < m - 1) ? kk : (m - 1);                           \
        s_[q] = __shfl(a, kc);                                          \
      }                                                                 \
      _Pragma("unroll")                                                 \
      for (int q = 0; q < 8; ++q) r_[q] = ROWS2[(size_t)s_[q] * 32 + c]; \
      half2v b2 = hz;                                                   \
      _Pragma("unroll")                                                 \
      for (int q = 0; q < 8; ++q) {                                     \
        bool ok = (k + 2 * q + eo) < m;                                 \
        PKBODY                                                          \
      }                                                                 \
      ax += (float)b2.x; ay += (float)b2.y;                             \
    }                                                                   \
  }

// ---------------------------------------------------------------------------
// conv1 gather over fp16 xw1p (pre-scaled by dinv[row]), packed:
//   t'[i] = dinv[i] * ( relu( dinv[i]*(sum_s xw1p[s] + xw1p[i]) + conv1_b ) . u )
// ---------------------------------------------------------------------------
__global__ __launch_bounds__(256) void k_gcn1_gather(const int* __restrict__ offb,
                                                     const int* __restrict__ offe,
                                                     const int* __restrict__ adj,
                                                     const __half* __restrict__ xw1p,
                                                     const float* __restrict__ dinv,
                                                     const float* __restrict__ conv1_b,
                                                     const float* __restrict__ sv,
                                                     float* __restrict__ tp) {
  int i = blockIdx.x * 4 + (threadIdx.x >> 6);
  if (i >= NN) return;
  int lane = threadIdx.x & 63;
  int c = lane & 31, eo = lane >> 5;
  const half2v hz = {(_Float16)0.f, (_Float16)0.f};
  const half2v* X2 = (const half2v*)xw1p;
  int beg = offb[i], end = offe[i];
  float ax = 0.f, ay = 0.f;
  GATHER_PK16(X2, { b2 += ok ? r_[q] : hz; })
  ax += __shfl_xor(ax, 32);
  ay += __shfl_xor(ay, 32);
  float di = dinv[i];
  half2v self2 = X2[(size_t)i * 32 + c];
  float r0 = fmaxf(fmaf(ax + (float)self2.x, di, conv1_b[2 * c]), 0.f);
  float r1 = fmaxf(fmaf(ay + (float)self2.y, di, conv1_b[2 * c + 1]), 0.f);
  float p = r0 * sv[2 * c] + r1 * sv[2 * c + 1];
  if (eo) p = 0.f;  // upper half duplicates lower
  p = waveReduceSum(p);
  if (lane == 0) tp[i] = p * di;
}

// ---------------------------------------------------------------------------
// Xe gather + batched matvec. 4 hyperedges/wave, grid 3125; packed gather.
// ---------------------------------------------------------------------------
__global__ __launch_bounds__(256) void k_xe_gather(const int* __restrict__ offb,
                                                   const int* __restrict__ offe,
                                                   const int* __restrict__ adj,
                                                   const __half* __restrict__ C,
                                                   const int* __restrict__ W2P,
                                                   const float* __restrict__ b2bias,
                                                   __half* __restrict__ B) {
  __shared__ float hp[4][4][64];
  int lane = threadIdx.x & 63, wv = threadIdx.x >> 6;
  int c = lane & 31, eo = lane >> 5;
  const half2v hz = {(_Float16)0.f, (_Float16)0.f};
  const half2v* C2 = (const half2v*)C;
  int base = (blockIdx.x * 4 + wv) * 4;
  if (base >= NH) return;
  int ncnt = NH - base; if (ncnt > 4) ncnt = 4;
  for (int n = 0; n < ncnt; ++n) {
    int e = base + n;
    int beg = offb[NN + e], end = offe[NN + e];
    float ax = 0.f, ay = 0.f;
    GATHER_PK16(C2, { b2 += ok ? r_[q] : hz; })
    ax += __shfl_xor(ax, 32);
    ay += __shfl_xor(ay, 32);
    if (!eo) {
      float sc = 1.0f / fmaxf((float)(end - beg), 1.f);
      hp[wv][n][2 * c] = ax * sc;
      hp[wv][n][2 * c + 1] = ay * sc;
    }
  }
  __builtin_amdgcn_wave_barrier();
  int l2 = lane & 31;
  int hvp[4];
#pragma unroll
  for (int n = 0; n < 4; ++n) {
    half2v p;
    p.x = (_Float16)hp[wv][n][2 * l2];
    p.y = (_Float16)hp[wv][n][2 * l2 + 1];
    hvp[n] = __builtin_bit_cast(int, p);
  }
  float bb = b2bias[lane];
  float acc[4];
#pragma unroll
  for (int n = 0; n < 4; ++n) acc[n] = bb;
  for (int kk = 0; kk < 32; ++kk) {
    half2v wp = __builtin_bit_cast(half2v, W2P[kk * 64 + lane]);
#pragma unroll
    for (int n = 0; n < 4; ++n) {
      half2v hb = __builtin_bit_cast(half2v, __builtin_amdgcn_readlane(hvp[n], kk));
      acc[n] = fdot2f(hb, wp, acc[n]);
    }
  }
#pragma unroll
  for (int n = 0; n < 4; ++n)
    if (n < ncnt) B[(size_t)(base + n) * 64 + lane] = (__half)acc[n];
}

// ---------------------------------------------------------------------------
// Final fused kernel. 8 nodes/wave, grid 3125; packed xv-gather.
// ---------------------------------------------------------------------------
__global__ __launch_bounds__(256) void k_final(const int* __restrict__ offb,
                                               const int* __restrict__ offe,
                                               const int* __restrict__ adj,
                                               const __half* __restrict__ A,
                                               const __half* __restrict__ B,
                                               const __half* __restrict__ h,
                                               const float* __restrict__ tp,
                                               const float* __restrict__ dinv,
                                               const int* __restrict__ WUP,
                                               const float* __restrict__ bu,
                                               const float* __restrict__ sv,
                                               float* __restrict__ out) {
  __shared__ float hp[4][8][64];
  __shared__ float sarr[4][8];
  int lane = threadIdx.x & 63, wv = threadIdx.x >> 6;
  int c = lane & 31, eo = lane >> 5;
  const half2v hz = {(_Float16)0.f, (_Float16)0.f};
  const half2v* A2 = (const half2v*)A;
  const half2v* B2 = (const half2v*)B;
  const half2v* H2 = (const half2v*)h;
  int base = (blockIdx.x * 4 + wv) * 8;
  if (base >= NN) return;
  int ncnt = NN - base; if (ncnt > 8) ncnt = 8;
  float c_all = sv[128];
  for (int n = 0; n < ncnt; ++n) {
    int i = base + n;
    half2v av2 = A2[(size_t)i * 32 + c];
    int beg = offb[NN + NH + i], end = offe[NN + NH + i];
    float ax = 0.f, ay = 0.f;
    GATHER_PK16(B2, {
      half2v s = av2 + r_[q];
      s = __builtin_elementwise_max(s, hz);
      b2 += ok ? s : hz;
    })
    ax += __shfl_xor(ax, 32);
    ay += __shfl_xor(ay, 32);
    if (!eo) {
      float sc = 0.5f / fmaxf((float)(end - beg), 1.f);
      half2v h2 = H2[(size_t)i * 32 + c];
      hp[wv][n][2 * c] = ax * sc + 0.5f * (float)h2.x;
      hp[wv][n][2 * c + 1] = ay * sc + 0.5f * (float)h2.y;
    }
    // gcn2 scalar gather over dst-CSR (all 64 lanes)
    float di = dinv[i];
    int db = offb[i], de = offe[i];
    float g = 0.f;
    for (int j = db + lane; j < de; j += 64) g += tp[adj[j]];
    float gr = waveReduceSum(g);
    if (lane == 0) sarr[wv][n] = gr * di + tp[i] * di + c_all;
  }
  __builtin_amdgcn_wave_barrier();
  int l2 = lane & 31;
  int hvp[8];
#pragma unroll
  for (int n = 0; n < 8; ++n) {
    half2v p;
    p.x = (_Float16)hp[wv][n][2 * l2];
    p.y = (_Float16)hp[wv][n][2 * l2 + 1];
    hvp[n] = __builtin_bit_cast(int, p);
  }
  float bb = bu[lane];
  float w2v = sv[64 + lane];
  float acc[8];
#pragma unroll
  for (int n = 0; n < 8; ++n) acc[n] = bb;
  for (int kk = 0; kk < 32; ++kk) {
    half2v wp = __builtin_bit_cast(half2v, WUP[kk * 64 + lane]);
#pragma unroll
    for (int n = 0; n < 8; ++n) {
      half2v hb = __builtin_bit_cast(half2v, __builtin_amdgcn_readlane(hvp[n], kk));
      acc[n] = fdot2f(hb, wp, acc[n]);
    }
  }
#pragma unroll
  for (int n = 0; n < 8; ++n) {
    if (n < ncnt) {
      float part = fmaxf(acc[n], 0.f) * w2v;
      float tot = waveReduceSum(part);
      if (lane == 0) out[base + n] = tot + sarr[wv][n];
    }
  }
}

// ---------------------------------------------------------------------------
extern "C" void kernel_launch(void* const* d_in, const int* in_sizes, int n_in,
                              void* d_out, int out_size, void* d_ws, size_t ws_size,
                              hipStream_t stream) {
  (void)in_sizes; (void)n_in; (void)out_size; (void)ws_size;
  const float* x       = (const float*)d_in[0];
  const int*   ei      = (const int*)d_in[1];
  const int*   hv      = (const int*)d_in[2];
  const int*   he      = (const int*)d_in[3];
  const float* conv1_W = (const float*)d_in[5];
  const float* conv1_b = (const float*)d_in[6];
  const float* conv2_W = (const float*)d_in[7];
  const float* conv2_b = (const float*)d_in[8];
  const float* lin_W   = (const float*)d_in[9];
  const float* lin_b   = (const float*)d_in[10];
  const float* W1      = (const float*)d_in[11];
  const float* b1      = (const float*)d_in[12];
  const float* W2      = (const float*)d_in[13];
  const float* b2      = (const float*)d_in[14];
  const float* Wu      = (const float*)d_in[15];
  const float* bu      = (const float*)d_in[16];
  const float* cls_W   = (const float*)d_in[17];
  const float* cls_b   = (const float*)d_in[18];
  const float* lp_W    = (const float*)d_in[19];
  const float* lp_b    = (const float*)d_in[20];
  const float* head_W  = (const float*)d_in[21];
  const float* head_b  = (const float*)d_in[22];
  const int* src = ei;
  const int* dst = ei + NE;
  float* out = (float*)d_out;

  // workspace layout: all intermediate N*64 streams fp16 (~60 MB total)
  __half* H16  = (__half*)d_ws;                         // NN*64 fp16  h
  __half* PH   = H16 + (size_t)NN * 64;                 // NN*64 fp16  xw1' then C
  __half* QH   = PH + (size_t)NN * 64;                  // NN*64 fp16  A
  __half* XEH  = QH + (size_t)NN * 64;                  // NH*64 fp16  B
  float* DINV  = (float*)(XEH + (size_t)NH * 64);       // NN
  float* TP    = DINV + NN;                 // NN   t' = t*dinv
  float* SV    = TP + NN;                   // 192
  int* WUP     = (int*)(SV + 192);          // 2048 packed fp16x2 Wu
  int* W2P     = WUP + 2048;                // 2048 packed fp16x2 W2[64:]
  int* GCUR    = W2P + 2048;                // NBUK
  int* OFFB    = GCUR + NBUK;               // NS
  int* OFFE    = OFFB + NS;                 // NS
  int* ADJ     = OFFE + NS;                 // NBUK*P2CAP (24 MB)

  hipMemsetAsync(GCUR, 0, NBUK * 4, stream);

  k_vecs<<<1, 64, 0, stream>>>(conv2_W, conv2_b, cls_W, cls_b, lp_W, lp_b, head_W, head_b, SV);
  k_pack<<<16, 256, 0, stream>>>(Wu, W2, WUP, W2P);

  // CSR build (strided buckets; no global scan pass)
  k_phase1<<<NWG1, 1024, 0, stream>>>(src, dst, he, hv, GCUR, ADJ);
  k_phase2<<<NBUK, 256, 0, stream>>>(GCUR, ADJ, OFFB, OFFE);
  k_dinv<<<(NN + 255) / 256, 256, 0, stream>>>(OFFB, OFFE, DINV);

  // dense: xw1' = (x @ conv1_W) * dinv[row]  (fp16); h = relu(x @ lin_W + lin_b) (fp16)
  k_gemm<128, false, false, true, float, __half><<<2048, 256, 0, stream>>>(x, conv1_W, nullptr, DINV, PH, NN);
  k_gemm<128, true, true, false, float, __half><<<2048, 256, 0, stream>>>(x, lin_W, lin_b, nullptr, H16, NN);

  // GCN branch collapsed to t' (conv2 folded into k_final)
  k_gcn1_gather<<<NN / 4, 256, 0, stream>>>(OFFB, OFFE, ADJ, PH, DINV, conv1_b, SV, TP);

  // hyper branch dense parts fused: C = h@W1+b1 (PH), A = h@W2[:64] (QH)
  k_gemm_dual<<<2048, 256, 0, stream>>>(H16, W1, b1, W2, PH, QH, NN);

  // 4 hyperedges per wave -> 3125 blocks
  k_xe_gather<<<3125, 256, 0, stream>>>(OFFB, OFFE, ADJ, PH, W2P, b2, XEH);

  // 8 nodes per wave -> 3125 blocks
  k_final<<<3125, 256, 0, stream>>>(OFFB, OFFE, ADJ, QH, XEH, H16, TP, DINV, WUP, bu, SV, out);
}

// Round 18
// 296.513 us; speedup vs baseline: 2.4289x; 1.2069x over previous
//
#include <hip/hip_runtime.h>
#include <hip/hip_fp16.h>

#define NN 100000   // nodes
#define NF 128      // input features
#define D  64       // hidden dim
#define NE 1600000  // edges
#define NZ 1000000  // hypergraph incidences
#define NH 50000    // hyperedges

#define NS (NN + NH + NN)          // 250000 concatenated id space
#define TOT (NE + 2 * NZ)          // 3600000 adjacency entries
#define NBUK 977                   // ceil(NS/256) buckets of 256 ids
#define NWG1 256                   // phase-1 workgroups
#define P2CAP 6144                 // bucket stride/capacity

typedef _Float16 half2v __attribute__((ext_vector_type(2)));

static __device__ __forceinline__ float waveReduceSum(float v) {
#pragma unroll
  for (int off = 32; off > 0; off >>= 1) v += __shfl_down(v, off);
  return v;
}

// Wave-uniform broadcast via readlane (VALU pipe, not ds_bpermute/LDS pipe).
static __device__ __forceinline__ float bcastf(float v, int l) {
  return __int_as_float(__builtin_amdgcn_readlane(__float_as_int(v), l));
}

#if __has_builtin(__builtin_amdgcn_fdot2)
static __device__ __forceinline__ float fdot2f(half2v a, half2v b, float c) {
  return __builtin_amdgcn_fdot2(a, b, c, false);
}
#else
static __device__ __forceinline__ float fdot2f(half2v a, half2v b, float c) {
  return fmaf((float)a.x, (float)b.x, fmaf((float)a.y, (float)b.y, c));
}
#endif

// ---------------------------------------------------------------------------
// sv[0:64)   u    = conv2_W @ v1          (v1 = lp_W[:64] @ head_W)
// sv[64:128) w2v  = cls_W  @ v2           (v2 = lp_W[64:] @ head_W)
// sv[128]    c_all= lp_b.head_W + head_b + conv2_b.v1 + cls_b.v2
// ---------------------------------------------------------------------------
__global__ void k_vecs(const float* __restrict__ conv2_W, const float* __restrict__ conv2_b,
                       const float* __restrict__ cls_W, const float* __restrict__ cls_b,
                       const float* __restrict__ lp_W, const float* __restrict__ lp_b,
                       const float* __restrict__ head_W, const float* __restrict__ head_b,
                       float* __restrict__ sv) {
  int t = threadIdx.x;  // 0..63, one wave
  __shared__ float v1[64], v2[64];
  float a1 = 0.f, a2 = 0.f;
  for (int c = 0; c < 64; ++c) {
    float hw = head_W[c];
    a1 = fmaf(lp_W[t * 64 + c], hw, a1);
    a2 = fmaf(lp_W[(64 + t) * 64 + c], hw, a2);
  }
  v1[t] = a1;
  v2[t] = a2;
  __syncthreads();
  float u = 0.f, w = 0.f;
  for (int c = 0; c < 64; ++c) {
    u = fmaf(conv2_W[t * 64 + c], v1[c], u);
    w = fmaf(cls_W[t * 64 + c], v2[c], w);
  }
  sv[t] = u;
  sv[64 + t] = w;
  float part = lp_b[t] * head_W[t] + conv2_b[t] * v1[t] + cls_b[t] * v2[t];
  part = waveReduceSum(part);
  if (t == 0) sv[128] = part + head_b[0];
}

// ---------------------------------------------------------------------------
// Pack weight matrices pairwise over k into fp16x2 tables:
//  [0,2048)      WUP  : Wu[2kk..][lane]
//  [2048,4096)   W2P  : W2[64+2kk..][lane]
//  [4096,8192)   C1P  : conv1_W (128x64, 64 pairs)
//  [8192,12288)  LWP  : lin_W   (128x64, 64 pairs)
//  [12288,14336) W1P  : W1      (64x64, 32 pairs)
//  [14336,16384) W2AP : W2[:64] (64x64, 32 pairs)
// ---------------------------------------------------------------------------
__global__ void k_pack(const float* __restrict__ Wu, const float* __restrict__ W2,
                       const float* __restrict__ conv1_W, const float* __restrict__ lin_W,
                       const float* __restrict__ W1,
                       int* __restrict__ PK) {
  int t = blockIdx.x * 256 + threadIdx.x;
  if (t >= 16384) return;
  const float* srcm;
  int idx, roff = 0;
  if (t < 2048)       { srcm = Wu;      idx = t;          }
  else if (t < 4096)  { srcm = W2;      idx = t - 2048;  roff = 64; }
  else if (t < 8192)  { srcm = conv1_W; idx = t - 4096;  }
  else if (t < 12288) { srcm = lin_W;   idx = t - 8192;  }
  else if (t < 14336) { srcm = W1;      idx = t - 12288; }
  else                { srcm = W2;      idx = t - 14336; }
  int kk = idx >> 6, lane = idx & 63;
  half2v p;
  p.x = (_Float16)srcm[(roff + 2 * kk) * 64 + lane];
  p.y = (_Float16)srcm[(roff + 2 * kk + 1) * 64 + lane];
  PK[t] = __builtin_bit_cast(int, p);
}

// ---------------------------------------------------------------------------
// Fused dual K=128 GEMM over x (read ONCE as float2):
//   xw1' = (x @ conv1_W) * dinv[row]  -> fp16
//   h    = relu(x @ lin_W + lin_b)    -> fp16
// lane holds x col-pair; packed weights; 64 x (readlane + 2 fdot2).
// ---------------------------------------------------------------------------
__global__ __launch_bounds__(256) void k_gemm128_dual(const float* __restrict__ x,
                                                      const int* __restrict__ C1P,
                                                      const int* __restrict__ LWP,
                                                      const float* __restrict__ lin_b,
                                                      const float* __restrict__ dinv,
                                                      __half* __restrict__ xw1p,
                                                      __half* __restrict__ h16, int nrows) {
  int lane = threadIdx.x & 63;
  int wave = threadIdx.x >> 6;
  int w1[64], w2[64];
#pragma unroll
  for (int k = 0; k < 64; ++k) {
    w1[k] = C1P[k * 64 + lane];
    w2[k] = LWP[k * 64 + lane];
  }
  float bb = lin_b[lane];
  int wid = blockIdx.x * 4 + wave;
  int nw = gridDim.x * 4;
  if (wid >= nrows) return;
  const float2* X2 = (const float2*)x;
  float2 v = X2[(size_t)wid * 64 + lane];
  for (int row = wid; row < nrows; row += nw) {
    int nrow = row + nw;
    float2 nv = make_float2(0.f, 0.f);
    if (nrow < nrows) nv = X2[(size_t)nrow * 64 + lane];
    half2v hv;
    hv.x = (_Float16)v.x;
    hv.y = (_Float16)v.y;
    int hvi = __builtin_bit_cast(int, hv);
    float a0 = 0.f, a1 = bb;
#pragma unroll
    for (int kk = 0; kk < 64; ++kk) {
      half2v xb = __builtin_bit_cast(half2v, __builtin_amdgcn_readlane(hvi, kk));
      a0 = fdot2f(xb, __builtin_bit_cast(half2v, w1[kk]), a0);
      a1 = fdot2f(xb, __builtin_bit_cast(half2v, w2[kk]), a1);
    }
    xw1p[(size_t)row * 64 + lane] = (__half)(a0 * dinv[row]);
    h16[(size_t)row * 64 + lane] = (__half)fmaxf(a1, 0.f);
    v = nv;
  }
}

// ---------------------------------------------------------------------------
// Fused dual K=64 GEMM over h (fp16, read once):
//   C = h@W1 + b1 (fp16), A = h@W2[:64] (fp16). 32 x (readlane + 2 fdot2).
// ---------------------------------------------------------------------------
__global__ __launch_bounds__(256) void k_gemm_dual(const __half* __restrict__ in,
                                                   const int* __restrict__ W1P,
                                                   const float* __restrict__ b1,
                                                   const int* __restrict__ W2AP,
                                                   __half* __restrict__ Cout,
                                                   __half* __restrict__ Aout, int nrows) {
  int lane = threadIdx.x & 63;
  int wave = threadIdx.x >> 6;
  int w1[32], w2[32];
#pragma unroll
  for (int k = 0; k < 32; ++k) {
    w1[k] = W1P[k * 64 + lane];
    w2[k] = W2AP[k * 64 + lane];
  }
  float bb = b1[lane];
  int wid = blockIdx.x * 4 + wave;
  int nw = gridDim.x * 4;
  if (wid >= nrows) return;
  const half2v* IN2 = (const half2v*)in;
  int c32 = lane & 31;
  half2v v = IN2[(size_t)wid * 32 + c32];
  for (int row = wid; row < nrows; row += nw) {
    int nrow = row + nw;
    half2v nv = {(_Float16)0.f, (_Float16)0.f};
    if (nrow < nrows) nv = IN2[(size_t)nrow * 32 + c32];
    int hvi = __builtin_bit_cast(int, v);
    float accC = bb, accA = 0.f;
#pragma unroll
    for (int kk = 0; kk < 32; ++kk) {
      half2v xb = __builtin_bit_cast(half2v, __builtin_amdgcn_readlane(hvi, kk));
      accC = fdot2f(xb, __builtin_bit_cast(half2v, w1[kk]), accC);
      accA = fdot2f(xb, __builtin_bit_cast(half2v, w2[kk]), accA);
    }
    Cout[(size_t)row * 64 + lane] = (__half)accC;
    Aout[(size_t)row * 64 + lane] = (__half)accA;
    v = nv;
  }
}

// ---------------------------------------------------------------------------
// CSR build (no global scan): fixed-stride buckets at b*P2CAP.
// ---------------------------------------------------------------------------
__global__ __launch_bounds__(1024) void k_phase1(const int* __restrict__ src,
                                                 const int* __restrict__ dst,
                                                 const int* __restrict__ he,
                                                 const int* __restrict__ hv,
                                                 int* __restrict__ gcur,
                                                 int* __restrict__ adj) {
  __shared__ int cnt[NBUK], base[NBUK], cur[NBUK];
  int tid = threadIdx.x;
  for (int b = tid; b < NBUK; b += 1024) { cnt[b] = 0; cur[b] = 0; }
  __syncthreads();
  int per = (TOT + NWG1 - 1) / NWG1;
  int s0 = blockIdx.x * per;
  int s1 = s0 + per; if (s1 > TOT) s1 = TOT;
  for (int j = s0 + tid; j < s1; j += 1024) {
    int id;
    if (j < NE) id = dst[j];
    else if (j < NE + NZ) id = NN + he[j - NE];
    else id = NN + NH + hv[j - NE - NZ];
    atomicAdd(&cnt[id >> 8], 1);
  }
  __syncthreads();
  for (int b = tid; b < NBUK; b += 1024) {
    int c = cnt[b];
    if (c) base[b] = b * P2CAP + atomicAdd(&gcur[b], c);
  }
  __syncthreads();
  for (int j = s0 + tid; j < s1; j += 1024) {
    int id, val;
    if (j < NE)           { id = dst[j];                val = src[j]; }
    else if (j < NE + NZ) { id = NN + he[j - NE];       val = hv[j - NE]; }
    else                  { id = NN + NH + hv[j - NE - NZ]; val = he[j - NE - NZ]; }
    int b = id >> 8;
    int slot = base[b] + atomicAdd(&cur[b], 1);
    adj[slot] = ((id & 255) << 17) | val;   // val < 131072
  }
}

__global__ __launch_bounds__(256) void k_phase2(const int* __restrict__ gcur,
                                                int* __restrict__ adj,
                                                int* __restrict__ offb,
                                                int* __restrict__ offe) {
  __shared__ int ent[P2CAP];
  __shared__ int hist[256];
  int b = blockIdx.x, tid = threadIdx.x;
  int s = b * P2CAP;
  int n = gcur[b];
  if (n > P2CAP) n = P2CAP;  // safety; cannot trigger on this dataset
  hist[tid] = 0;
  __syncthreads();
  for (int k = tid; k < n; k += 256) {
    int v = adj[s + k];
    ent[k] = v;
    atomicAdd(&hist[v >> 17], 1);
  }
  __syncthreads();
  int c = hist[tid];
#pragma unroll
  for (int d = 1; d < 256; d <<= 1) {
    int x = (tid >= d) ? hist[tid - d] : 0;
    __syncthreads();
    hist[tid] += x;
    __syncthreads();
  }
  int excl = hist[tid] - c;
  hist[tid] = excl;
  int gid = (b << 8) + tid;
  if (gid < NS) {
    offb[gid] = s + excl;
    offe[gid] = s + excl + c;
  }
  __syncthreads();
  for (int k = tid; k < n; k += 256) {
    int v = ent[k];
    int pos = atomicAdd(&hist[v >> 17], 1);
    adj[s + pos] = v & 0x1FFFF;   // store bare value
  }
}

__global__ void k_dinv(const int* __restrict__ offb, const int* __restrict__ offe,
                       float* __restrict__ dinv) {
  int i = blockIdx.x * 256 + threadIdx.x;
  if (i < NN) dinv[i] = rsqrtf((float)(offe[i] - offb[i] + 1));  // +1 self-loop
}

// ---------------------------------------------------------------------------
// Packed-fp16 gather: 64 lanes = 32 col-pairs (c) x 2 element-slots (eo).
// ---------------------------------------------------------------------------
#define GATHER_PK16(ROWS2, PKBODY)                                      \
  for (int j0 = beg; j0 < end; j0 += 64) {                              \
    int m = end - j0; if (m > 64) m = 64;                               \
    int a = (lane < m) ? adj[j0 + lane] : 0;                            \
    for (int k = 0; k < m; k += 16) {                                   \
      int s_[8]; half2v r_[8];                                          \
      _Pragma("unroll")                                                 \
      for (int q = 0; q < 8; ++q) {                                     \
        int kk = k + 2 * q + eo;                                        \
        int kc = (kk < m - 1) ? kk : (m - 1);                           \
        s_[q] = __shfl(a, kc);                                          \
      }                                                                 \
      _Pragma("unroll")                                                 \
      for (int q = 0; q < 8; ++q) r_[q] = ROWS2[(size_t)s_[q] * 32 + c]; \
      half2v b2 = hz;                                                   \
      _Pragma("unroll")                                                 \
      for (int q = 0; q < 8; ++q) {                                     \
        bool ok = (k + 2 * q + eo) < m;                                 \
        PKBODY                                                          \
      }                                                                 \
      ax += (float)b2.x; ay += (float)b2.y;                             \
    }                                                                   \
  }

// ---------------------------------------------------------------------------
// conv1 gather over fp16 xw1p (pre-scaled by dinv[row]), packed:
//   t'[i] = dinv[i] * ( relu( dinv[i]*(sum_s xw1p[s] + xw1p[i]) + conv1_b ) . u )
// ---------------------------------------------------------------------------
__global__ __launch_bounds__(256) void k_gcn1_gather(const int* __restrict__ offb,
                                                     const int* __restrict__ offe,
                                                     const int* __restrict__ adj,
                                                     const __half* __restrict__ xw1p,
                                                     const float* __restrict__ dinv,
                                                     const float* __restrict__ conv1_b,
                                                     const float* __restrict__ sv,
                                                     float* __restrict__ tp) {
  int i = blockIdx.x * 4 + (threadIdx.x >> 6);
  if (i >= NN) return;
  int lane = threadIdx.x & 63;
  int c = lane & 31, eo = lane >> 5;
  const half2v hz = {(_Float16)0.f, (_Float16)0.f};
  const half2v* X2 = (const half2v*)xw1p;
  int beg = offb[i], end = offe[i];
  float ax = 0.f, ay = 0.f;
  GATHER_PK16(X2, { b2 += ok ? r_[q] : hz; })
  ax += __shfl_xor(ax, 32);
  ay += __shfl_xor(ay, 32);
  float di = dinv[i];
  half2v self2 = X2[(size_t)i * 32 + c];
  float r0 = fmaxf(fmaf(ax + (float)self2.x, di, conv1_b[2 * c]), 0.f);
  float r1 = fmaxf(fmaf(ay + (float)self2.y, di, conv1_b[2 * c + 1]), 0.f);
  float p = r0 * sv[2 * c] + r1 * sv[2 * c + 1];
  if (eo) p = 0.f;  // upper half duplicates lower
  p = waveReduceSum(p);
  if (lane == 0) tp[i] = p * di;
}

// ---------------------------------------------------------------------------
// Xe gather + batched matvec. 4 hyperedges/wave, grid 3125; packed gather.
// ---------------------------------------------------------------------------
__global__ __launch_bounds__(256) void k_xe_gather(const int* __restrict__ offb,
                                                   const int* __restrict__ offe,
                                                   const int* __restrict__ adj,
                                                   const __half* __restrict__ C,
                                                   const int* __restrict__ W2P,
                                                   const float* __restrict__ b2bias,
                                                   __half* __restrict__ B) {
  __shared__ float hp[4][4][64];
  int lane = threadIdx.x & 63, wv = threadIdx.x >> 6;
  int c = lane & 31, eo = lane >> 5;
  const half2v hz = {(_Float16)0.f, (_Float16)0.f};
  const half2v* C2 = (const half2v*)C;
  int base = (blockIdx.x * 4 + wv) * 4;
  if (base >= NH) return;
  int ncnt = NH - base; if (ncnt > 4) ncnt = 4;
  for (int n = 0; n < ncnt; ++n) {
    int e = base + n;
    int beg = offb[NN + e], end = offe[NN + e];
    float ax = 0.f, ay = 0.f;
    GATHER_PK16(C2, { b2 += ok ? r_[q] : hz; })
    ax += __shfl_xor(ax, 32);
    ay += __shfl_xor(ay, 32);
    if (!eo) {
      float sc = 1.0f / fmaxf((float)(end - beg), 1.f);
      hp[wv][n][2 * c] = ax * sc;
      hp[wv][n][2 * c + 1] = ay * sc;
    }
  }
  __builtin_amdgcn_wave_barrier();
  int l2 = lane & 31;
  int hvp[4];
#pragma unroll
  for (int n = 0; n < 4; ++n) {
    half2v p;
    p.x = (_Float16)hp[wv][n][2 * l2];
    p.y = (_Float16)hp[wv][n][2 * l2 + 1];
    hvp[n] = __builtin_bit_cast(int, p);
  }
  float bb = b2bias[lane];
  float acc[4];
#pragma unroll
  for (int n = 0; n < 4; ++n) acc[n] = bb;
  for (int kk = 0; kk < 32; ++kk) {
    half2v wp = __builtin_bit_cast(half2v, W2P[kk * 64 + lane]);
#pragma unroll
    for (int n = 0; n < 4; ++n) {
      half2v hb = __builtin_bit_cast(half2v, __builtin_amdgcn_readlane(hvp[n], kk));
      acc[n] = fdot2f(hb, wp, acc[n]);
    }
  }
#pragma unroll
  for (int n = 0; n < 4; ++n)
    if (n < ncnt) B[(size_t)(base + n) * 64 + lane] = (__half)acc[n];
}

// ---------------------------------------------------------------------------
// Final fused kernel. 8 nodes/wave, grid 3125; packed xv-gather.
// ---------------------------------------------------------------------------
__global__ __launch_bounds__(256) void k_final(const int* __restrict__ offb,
                                               const int* __restrict__ offe,
                                               const int* __restrict__ adj,
                                               const __half* __restrict__ A,
                                               const __half* __restrict__ B,
                                               const __half* __restrict__ h,
                                               const float* __restrict__ tp,
                                               const float* __restrict__ dinv,
                                               const int* __restrict__ WUP,
                                               const float* __restrict__ bu,
                                               const float* __restrict__ sv,
                                               float* __restrict__ out) {
  __shared__ float hp[4][8][64];
  __shared__ float sarr[4][8];
  int lane = threadIdx.x & 63, wv = threadIdx.x >> 6;
  int c = lane & 31, eo = lane >> 5;
  const half2v hz = {(_Float16)0.f, (_Float16)0.f};
  const half2v* A2 = (const half2v*)A;
  const half2v* B2 = (const half2v*)B;
  const half2v* H2 = (const half2v*)h;
  int base = (blockIdx.x * 4 + wv) * 8;
  if (base >= NN) return;
  int ncnt = NN - base; if (ncnt > 8) ncnt = 8;
  float c_all = sv[128];
  for (int n = 0; n < ncnt; ++n) {
    int i = base + n;
    half2v av2 = A2[(size_t)i * 32 + c];
    int beg = offb[NN + NH + i], end = offe[NN + NH + i];
    float ax = 0.f, ay = 0.f;
    GATHER_PK16(B2, {
      half2v s = av2 + r_[q];
      s = __builtin_elementwise_max(s, hz);
      b2 += ok ? s : hz;
    })
    ax += __shfl_xor(ax, 32);
    ay += __shfl_xor(ay, 32);
    if (!eo) {
      float sc = 0.5f / fmaxf((float)(end - beg), 1.f);
      half2v h2 = H2[(size_t)i * 32 + c];
      hp[wv][n][2 * c] = ax * sc + 0.5f * (float)h2.x;
      hp[wv][n][2 * c + 1] = ay * sc + 0.5f * (float)h2.y;
    }
    // gcn2 scalar gather over dst-CSR (all 64 lanes)
    float di = dinv[i];
    int db = offb[i], de = offe[i];
    float g = 0.f;
    for (int j = db + lane; j < de; j += 64) g += tp[adj[j]];
    float gr = waveReduceSum(g);
    if (lane == 0) sarr[wv][n] = gr * di + tp[i] * di + c_all;
  }
  __builtin_amdgcn_wave_barrier();
  int l2 = lane & 31;
  int hvp[8];
#pragma unroll
  for (int n = 0; n < 8; ++n) {
    half2v p;
    p.x = (_Float16)hp[wv][n][2 * l2];
    p.y = (_Float16)hp[wv][n][2 * l2 + 1];
    hvp[n] = __builtin_bit_cast(int, p);
  }
  float bb = bu[lane];
  float w2v = sv[64 + lane];
  float acc[8];
#pragma unroll
  for (int n = 0; n < 8; ++n) acc[n] = bb;
  for (int kk = 0; kk < 32; ++kk) {
    half2v wp = __builtin_bit_cast(half2v, WUP[kk * 64 + lane]);
#pragma unroll
    for (int n = 0; n < 8; ++n) {
      half2v hb = __builtin_bit_cast(half2v, __builtin_amdgcn_readlane(hvp[n], kk));
      acc[n] = fdot2f(hb, wp, acc[n]);
    }
  }
#pragma unroll
  for (int n = 0; n < 8; ++n) {
    if (n < ncnt) {
      float part = fmaxf(acc[n], 0.f) * w2v;
      float tot = waveReduceSum(part);
      if (lane == 0) out[base + n] = tot + sarr[wv][n];
    }
  }
}

// ---------------------------------------------------------------------------
extern "C" void kernel_launch(void* const* d_in, const int* in_sizes, int n_in,
                              void* d_out, int out_size, void* d_ws, size_t ws_size,
                              hipStream_t stream) {
  (void)in_sizes; (void)n_in; (void)out_size; (void)ws_size;
  const float* x       = (const float*)d_in[0];
  const int*   ei      = (const int*)d_in[1];
  const int*   hv      = (const int*)d_in[2];
  const int*   he      = (const int*)d_in[3];
  const float* conv1_W = (const float*)d_in[5];
  const float* conv1_b = (const float*)d_in[6];
  const float* conv2_W = (const float*)d_in[7];
  const float* conv2_b = (const float*)d_in[8];
  const float* lin_W   = (const float*)d_in[9];
  const float* lin_b   = (const float*)d_in[10];
  const float* W1      = (const float*)d_in[11];
  const float* b1      = (const float*)d_in[12];
  const float* W2      = (const float*)d_in[13];
  const float* b2      = (const float*)d_in[14];
  const float* Wu      = (const float*)d_in[15];
  const float* bu      = (const float*)d_in[16];
  const float* cls_W   = (const float*)d_in[17];
  const float* cls_b   = (const float*)d_in[18];
  const float* lp_W    = (const float*)d_in[19];
  const float* lp_b    = (const float*)d_in[20];
  const float* head_W  = (const float*)d_in[21];
  const float* head_b  = (const float*)d_in[22];
  const int* src = ei;
  const int* dst = ei + NE;
  float* out = (float*)d_out;

  // workspace layout
  __half* H16  = (__half*)d_ws;                         // NN*64 fp16  h
  __half* PH   = H16 + (size_t)NN * 64;                 // NN*64 fp16  xw1' then C
  __half* QH   = PH + (size_t)NN * 64;                  // NN*64 fp16  A
  __half* XEH  = QH + (size_t)NN * 64;                  // NH*64 fp16  B
  float* DINV  = (float*)(XEH + (size_t)NH * 64);       // NN
  float* TP    = DINV + NN;                 // NN   t' = t*dinv
  float* SV    = TP + NN;                   // 192
  int* PK      = (int*)(SV + 192);          // 16384 packed fp16x2 weight tables
  int* WUP     = PK;                        //  [0,2048)
  int* W2P     = PK + 2048;                 //  [2048,4096)
  int* C1P     = PK + 4096;                 //  [4096,8192)
  int* LWP     = PK + 8192;                 //  [8192,12288)
  int* W1P     = PK + 12288;                //  [12288,14336)
  int* W2AP    = PK + 14336;                //  [14336,16384)
  int* GCUR    = PK + 16384;                // NBUK
  int* OFFB    = GCUR + NBUK;               // NS
  int* OFFE    = OFFB + NS;                 // NS
  int* ADJ     = OFFE + NS;                 // NBUK*P2CAP (24 MB)

  hipMemsetAsync(GCUR, 0, NBUK * 4, stream);

  k_vecs<<<1, 64, 0, stream>>>(conv2_W, conv2_b, cls_W, cls_b, lp_W, lp_b, head_W, head_b, SV);
  k_pack<<<64, 256, 0, stream>>>(Wu, W2, conv1_W, lin_W, W1, PK);

  // CSR build (strided buckets; no global scan pass)
  k_phase1<<<NWG1, 1024, 0, stream>>>(src, dst, he, hv, GCUR, ADJ);
  k_phase2<<<NBUK, 256, 0, stream>>>(GCUR, ADJ, OFFB, OFFE);
  k_dinv<<<(NN + 255) / 256, 256, 0, stream>>>(OFFB, OFFE, DINV);

  // dense: xw1' and h in ONE pass over x
  k_gemm128_dual<<<2048, 256, 0, stream>>>(x, C1P, LWP, lin_b, DINV, PH, H16, NN);

  // GCN branch collapsed to t' (conv2 folded into k_final)
  k_gcn1_gather<<<NN / 4, 256, 0, stream>>>(OFFB, OFFE, ADJ, PH, DINV, conv1_b, SV, TP);

  // hyper branch dense parts fused: C = h@W1+b1 (PH), A = h@W2[:64] (QH)
  k_gemm_dual<<<2048, 256, 0, stream>>>(H16, W1P, b1, W2AP, PH, QH, NN);

  // 4 hyperedges per wave -> 3125 blocks
  k_xe_gather<<<3125, 256, 0, stream>>>(OFFB, OFFE, ADJ, PH, W2P, b2, XEH);

  // 8 nodes per wave -> 3125 blocks
  k_final<<<3125, 256, 0, stream>>>(OFFB, OFFE, ADJ, QH, XEH, H16, TP, DINV, WUP, bu, SV, out);
}